// Round 5
// baseline (153.807 us; speedup 1.0000x reference)
//
#include <hip/hip_runtime.h>

typedef __bf16 bf16x8 __attribute__((ext_vector_type(8)));
typedef float f32x4 __attribute__((ext_vector_type(4)));
typedef float f32x16 __attribute__((ext_vector_type(16)));

#define S_LEN 4096

__device__ __forceinline__ unsigned short f2bf(float f) {
    unsigned int u = __float_as_uint(f);
    u += 0x7fffu + ((u >> 16) & 1u);
    return (unsigned short)(u >> 16);
}

__device__ __forceinline__ unsigned int pk_bf16(float lo, float hi) {
    unsigned int r;
    asm("v_cvt_pk_bf16_f32 %0, %1, %2" : "=v"(r) : "v"(lo), "v"(hi));
    return r;
}

// ---------- weight conversion ----------
__global__ void k_conv_w(const float* __restrict__ Wq, const float* __restrict__ Wkv,
                         const float* __restrict__ Wp, unsigned short* __restrict__ wb,
                         unsigned short* __restrict__ wpb) {
    int stride = gridDim.x * blockDim.x;
    for (int i = blockIdx.x * blockDim.x + threadIdx.x; i < 262144; i += stride) {
        if (i < 65536)       wb[i]           = f2bf(Wq[i]);
        else if (i < 196608) wb[i]           = f2bf(Wkv[i - 65536]);
        else                 wpb[i - 196608] = f2bf(Wp[i - 196608]);
    }
}

// ---------- x (b,c,s) f32 -> xT (b,s,c) bf16 ----------
__global__ __launch_bounds__(256) void k_xt(const float* __restrict__ x, unsigned short* __restrict__ xT) {
    __shared__ unsigned short tile[64 * 80];
    const int b = blockIdx.z, c0 = blockIdx.y * 64, s0 = blockIdx.x * 64;
    const int tid = threadIdx.x;
#pragma unroll
    for (int ii = 0; ii < 4; ++ii) {
        int flat = ii * 256 + tid;
        int cr = flat >> 4, s4 = flat & 15;
        const float4 v = *(const float4*)(x + ((size_t)(b * 256 + c0 + cr)) * S_LEN + s0 + s4 * 4);
        tile[(s4 * 4 + 0) * 80 + cr] = f2bf(v.x);
        tile[(s4 * 4 + 1) * 80 + cr] = f2bf(v.y);
        tile[(s4 * 4 + 2) * 80 + cr] = f2bf(v.z);
        tile[(s4 * 4 + 3) * 80 + cr] = f2bf(v.w);
    }
    __syncthreads();
#pragma unroll
    for (int ii = 0; ii < 2; ++ii) {
        int flat = ii * 256 + tid;
        int sr = flat >> 3, ch = flat & 7;
        uint4 u = *(const uint4*)&tile[sr * 80 + ch * 8];
        *(uint4*)(xT + ((size_t)(b * 4096 + s0 + sr)) * 256 + c0 + ch * 8) = u;
    }
}

// ---------- QKV GEMM -> q (pre-scaled) / k [b][h][s][32], v [b][h][32][s] ----------
__global__ __launch_bounds__(256) void k_qkv(const unsigned short* __restrict__ wb,
                                             const unsigned short* __restrict__ xT,
                                             const float* __restrict__ bq,
                                             const float* __restrict__ bkv,
                                             unsigned short* __restrict__ qws,
                                             unsigned short* __restrict__ kws,
                                             unsigned short* __restrict__ vws) {
    __shared__ unsigned short As[128 * 32];
    __shared__ unsigned short Bs[128 * 32];
    const int b = blockIdx.z;
    const int o0 = blockIdx.y * 128, s0 = blockIdx.x * 128;
    const int tid = threadIdx.x;
    const int w = tid >> 6, l = tid & 63, g = l >> 4, lc = l & 15;
    const int wr = w >> 1, wc = w & 1;
    const unsigned short* xb = xT + (size_t)b * 4096 * 256;
    const float SM_C = 0.25505654458f;  // log2(e)/sqrt(32) folded into q

    f32x4 acc[4][4];
#pragma unroll
    for (int m = 0; m < 4; ++m)
#pragma unroll
        for (int nf = 0; nf < 4; ++nf) acc[m][nf] = (f32x4)(0.f);

    const int lrow = tid >> 1, lhalf = tid & 1;
    const int lsw0 = (lrow * 64 + lhalf * 32) ^ ((lrow & 7) << 4);
    const int lsw1 = (lrow * 64 + lhalf * 32 + 16) ^ ((lrow & 7) << 4);

    for (int kk = 0; kk < 8; ++kk) {
        const int c0 = kk * 32;
        __syncthreads();
        {
            const uint4* srcA = (const uint4*)(wb + (size_t)(o0 + lrow) * 256 + c0 + lhalf * 16);
            uint4 a0 = srcA[0], a1 = srcA[1];
            const uint4* srcB = (const uint4*)(xb + (size_t)(s0 + lrow) * 256 + c0 + lhalf * 16);
            uint4 b0 = srcB[0], b1 = srcB[1];
            *(uint4*)((char*)As + lsw0) = a0;
            *(uint4*)((char*)As + lsw1) = a1;
            *(uint4*)((char*)Bs + lsw0) = b0;
            *(uint4*)((char*)Bs + lsw1) = b1;
        }
        __syncthreads();
        bf16x8 af[4], bfv[4];
#pragma unroll
        for (int m = 0; m < 4; ++m) {
            int row = wr * 64 + m * 16 + lc;
            af[m] = *(const bf16x8*)((char*)As + ((row * 64 + g * 16) ^ ((row & 7) << 4)));
        }
#pragma unroll
        for (int nf = 0; nf < 4; ++nf) {
            int row = wc * 64 + nf * 16 + lc;
            bfv[nf] = *(const bf16x8*)((char*)Bs + ((row * 64 + g * 16) ^ ((row & 7) << 4)));
        }
#pragma unroll
        for (int m = 0; m < 4; ++m)
#pragma unroll
            for (int nf = 0; nf < 4; ++nf)
                acc[m][nf] = __builtin_amdgcn_mfma_f32_16x16x32_bf16(af[m], bfv[nf], acc[m][nf], 0, 0, 0);
    }

#pragma unroll
    for (int m = 0; m < 4; ++m)
#pragma unroll
        for (int nf = 0; nf < 4; ++nf)
#pragma unroll
            for (int i = 0; i < 4; ++i) {
                int o = o0 + wr * 64 + m * 16 + g * 4 + i;
                int s = s0 + wc * 64 + nf * 16 + lc;
                if (o < 256) {
                    int h = o >> 5, d = o & 31;
                    qws[(((size_t)(b * 8 + h)) * 4096 + s) * 32 + d] = f2bf((acc[m][nf][i] + bq[o]) * SM_C);
                } else if (o < 512) {
                    int oo = o - 256, h = oo >> 5, d = oo & 31;
                    kws[(((size_t)(b * 8 + h)) * 4096 + s) * 32 + d] = f2bf(acc[m][nf][i] + bkv[o - 256]);
                } else {
                    int oo = o - 512, h = oo >> 5, d = oo & 31;
                    vws[(((size_t)(b * 8 + h)) * 32 + d) * 4096 + s] = f2bf(acc[m][nf][i] + bkv[o - 256]);
                }
            }
}

// ---------- causal flash attention: k-split across 4 waves, LDS combine ----------
__device__ __forceinline__ void attn_partial(int tile, int k0, int k1, int lane31, int hh,
                                             const unsigned short* __restrict__ qw_bh,
                                             const unsigned short* __restrict__ kw_bh,
                                             const unsigned short* __restrict__ vw_bh,
                                             f32x16& o, float& psum) {
    f32x16 sums, zf;
#pragma unroll
    for (int r = 0; r < 16; ++r) { o[r] = 0.f; sums[r] = 0.f; zf[r] = 0.f; }

    if (k0 < k1) {
        union OU { unsigned int u[4]; bf16x8 v; };
        OU onesU;
#pragma unroll
        for (int j = 0; j < 4; ++j) onesU.u[j] = 0x3F803F80u;  // bf16 1.0 x2
        const bf16x8 ones = onesU.v;

        const size_t qoff = (size_t)(tile * 32 + lane31) * 32 + hh * 8;
        const bf16x8 qf0 = *(const bf16x8*)(qw_bh + qoff);
        const bf16x8 qf1 = *(const bf16x8*)(qw_bh + qoff + 16);

        const unsigned short* kp = kw_bh + lane31 * 32 + hh * 8 + (size_t)k0 * 1024;
        const unsigned short* vp = vw_bh + (size_t)lane31 * 4096 + hh * 8 + k0 * 32;

        bf16x8 kf0 = *(const bf16x8*)(kp);
        bf16x8 kf1 = *(const bf16x8*)(kp + 16);
        bf16x8 vf0 = *(const bf16x8*)(vp);
        bf16x8 vf1 = *(const bf16x8*)(vp + 16);

#define ATTN_BODY(KT, KF0, KF1, VF0, VF1)                                              \
        {                                                                               \
            f32x16 s = __builtin_amdgcn_mfma_f32_32x32x16_bf16(KF0, qf0, zf, 0, 0, 0);  \
            s = __builtin_amdgcn_mfma_f32_32x32x16_bf16(KF1, qf1, s, 0, 0, 0);          \
            if ((KT) == tile) {                                                         \
                _Pragma("unroll")                                                       \
                for (int r = 0; r < 16; ++r) {                                          \
                    int krel = (r & 3) + 8 * (r >> 2) + 4 * hh;                         \
                    if (krel > lane31) s[r] = -1e30f;                                   \
                }                                                                       \
            }                                                                           \
            float p[16];                                                                \
            _Pragma("unroll")                                                           \
            for (int r = 0; r < 16; ++r) p[r] = __builtin_amdgcn_exp2f(s[r]);           \
            unsigned int c00 = pk_bf16(p[0], p[1]),   c01 = pk_bf16(p[2], p[3]);        \
            unsigned int c10 = pk_bf16(p[4], p[5]),   c11 = pk_bf16(p[6], p[7]);        \
            unsigned int c20 = pk_bf16(p[8], p[9]),   c21 = pk_bf16(p[10], p[11]);      \
            unsigned int c30 = pk_bf16(p[12], p[13]), c31 = pk_bf16(p[14], p[15]);      \
            asm("v_permlane32_swap_b32 %0, %1" : "+v"(c00), "+v"(c10));                 \
            asm("v_permlane32_swap_b32 %0, %1" : "+v"(c01), "+v"(c11));                 \
            asm("v_permlane32_swap_b32 %0, %1" : "+v"(c20), "+v"(c30));                 \
            asm("v_permlane32_swap_b32 %0, %1" : "+v"(c21), "+v"(c31));                 \
            union U { uint4 u; bf16x8 v; };                                             \
            U pa0, pa1;                                                                 \
            pa0.u = make_uint4(c00, c01, c10, c11);                                     \
            pa1.u = make_uint4(c20, c21, c30, c31);                                     \
            sums = __builtin_amdgcn_mfma_f32_32x32x16_bf16(ones, pa0.v, sums, 0, 0, 0); \
            sums = __builtin_amdgcn_mfma_f32_32x32x16_bf16(ones, pa1.v, sums, 0, 0, 0); \
            o = __builtin_amdgcn_mfma_f32_32x32x16_bf16(VF0, pa0.v, o, 0, 0, 0);        \
            o = __builtin_amdgcn_mfma_f32_32x32x16_bf16(VF1, pa1.v, o, 0, 0, 0);        \
        }

        for (int kt = k0; kt < k1 - 1; ++kt) {
            kp += 1024;
            vp += 32;
            bf16x8 nkf0 = *(const bf16x8*)(kp);
            bf16x8 nkf1 = *(const bf16x8*)(kp + 16);
            bf16x8 nvf0 = *(const bf16x8*)(vp);
            bf16x8 nvf1 = *(const bf16x8*)(vp + 16);
            ATTN_BODY(kt, kf0, kf1, vf0, vf1)
            kf0 = nkf0; kf1 = nkf1; vf0 = nvf0; vf1 = nvf1;
        }
        ATTN_BODY(k1 - 1, kf0, kf1, vf0, vf1)
#undef ATTN_BODY
    }
    psum = sums[0];
}

__global__ __launch_bounds__(256) void k_attn(const unsigned short* __restrict__ qw,
                                              const unsigned short* __restrict__ kw,
                                              const unsigned short* __restrict__ vw,
                                              unsigned short* __restrict__ att) {
    __shared__ float po[2][4][64][17];

    const int tid = threadIdx.x;
    const int w = tid >> 6, l = tid & 63;
    const int lane31 = l & 31, hh = l >> 5;

    // XCD-aware: blockIdx%8 -> XCD (validated R4: 10x fetch drop). 4 bh per XCD.
    const int B = blockIdx.x;
    const int xcd = B & 7, slot = B >> 3;          // slot 0..255
    const int bh = xcd * 4 + (slot >> 6);          // 0..31
    const int pp = slot & 63;                      // pair index 0..63

    const int tA = pp, tB = 127 - pp;
    const int nA = pp + 1;                         // iters for tile A
    // concatenated range [0,129): [0,nA) -> tile A, [nA,129) -> tile B
    const int lo = w * 32;
    const int hi = (w == 3) ? 129 : (w + 1) * 32;

    const unsigned short* qw_bh = qw + (size_t)bh * 4096 * 32;
    const unsigned short* kw_bh = kw + (size_t)bh * 4096 * 32;
    const unsigned short* vw_bh = vw + (size_t)bh * 32 * 4096;

    f32x16 o;
    float ps;
    // segment of tile A
    {
        int k0 = lo, k1 = (hi < nA) ? hi : nA;
        attn_partial(tA, k0, k1, lane31, hh, qw_bh, kw_bh, vw_bh, o, ps);
        float* sp = &po[0][w][l][0];
#pragma unroll
        for (int r = 0; r < 16; ++r) sp[r] = o[r];
        sp[16] = ps;
    }
    // segment of tile B
    {
        int k0 = (lo > nA) ? (lo - nA) : 0;
        int k1 = hi - nA;   // hi>nA guaranteed false only for w=0 when nA>=32
        attn_partial(tB, k0, k1, lane31, hh, qw_bh, kw_bh, vw_bh, o, ps);
        float* sp = &po[1][w][l][0];
#pragma unroll
        for (int r = 0; r < 16; ++r) sp[r] = o[r];
        sp[16] = ps;
    }
    __syncthreads();

    if (w < 2) {
        const int tile = (w == 0) ? tA : tB;
        f32x16 tot;
        float den = 0.f;
#pragma unroll
        for (int r = 0; r < 16; ++r) tot[r] = 0.f;
#pragma unroll
        for (int ww = 0; ww < 4; ++ww) {
            const float* sp = &po[w][ww][l][0];
#pragma unroll
            for (int r = 0; r < 16; ++r) tot[r] += sp[r];
            den += sp[16];
        }
        const float inv = 1.0f / den;
        const int q = tile * 32 + lane31;
        unsigned int* dst = (unsigned int*)(att + (((size_t)(bh >> 3)) * 4096 + q) * 256 + (bh & 7) * 32);
#pragma unroll
        for (int j = 0; j < 8; ++j) {
            unsigned int v = pk_bf16(tot[2 * j] * inv, tot[2 * j + 1] * inv);
            dst[(j & 1) + 4 * (j >> 1) + 2 * hh] = v;
        }
    }
}

// ---------- output projection ----------
__global__ __launch_bounds__(256) void k_proj(const unsigned short* __restrict__ wpb,
                                              const unsigned short* __restrict__ att,
                                              const float* __restrict__ bp,
                                              float* __restrict__ out) {
    __shared__ unsigned short As[128 * 32];
    __shared__ unsigned short Bs[128 * 32];
    const int b = blockIdx.z;
    const int o0 = blockIdx.y * 128, s0 = blockIdx.x * 128;
    const int tid = threadIdx.x;
    const int w = tid >> 6, l = tid & 63, g = l >> 4, lc = l & 15;
    const int wr = w >> 1, wc = w & 1;
    const unsigned short* ab = att + (size_t)b * 4096 * 256;

    f32x4 acc[4][4];
#pragma unroll
    for (int m = 0; m < 4; ++m)
#pragma unroll
        for (int nf = 0; nf < 4; ++nf) acc[m][nf] = (f32x4)(0.f);

    const int lrow = tid >> 1, lhalf = tid & 1;
    const int lsw0 = (lrow * 64 + lhalf * 32) ^ ((lrow & 7) << 4);
    const int lsw1 = (lrow * 64 + lhalf * 32 + 16) ^ ((lrow & 7) << 4);

    for (int kk = 0; kk < 8; ++kk) {
        const int c0 = kk * 32;
        __syncthreads();
        {
            const uint4* srcA = (const uint4*)(wpb + (size_t)(o0 + lrow) * 256 + c0 + lhalf * 16);
            uint4 a0 = srcA[0], a1 = srcA[1];
            const uint4* srcB = (const uint4*)(ab + (size_t)(s0 + lrow) * 256 + c0 + lhalf * 16);
            uint4 b0 = srcB[0], b1 = srcB[1];
            *(uint4*)((char*)As + lsw0) = a0;
            *(uint4*)((char*)As + lsw1) = a1;
            *(uint4*)((char*)Bs + lsw0) = b0;
            *(uint4*)((char*)Bs + lsw1) = b1;
        }
        __syncthreads();
        bf16x8 af[4], bfv[4];
#pragma unroll
        for (int m = 0; m < 4; ++m) {
            int row = wr * 64 + m * 16 + lc;
            af[m] = *(const bf16x8*)((char*)As + ((row * 64 + g * 16) ^ ((row & 7) << 4)));
        }
#pragma unroll
        for (int nf = 0; nf < 4; ++nf) {
            int row = wc * 64 + nf * 16 + lc;
            bfv[nf] = *(const bf16x8*)((char*)Bs + ((row * 64 + g * 16) ^ ((row & 7) << 4)));
        }
#pragma unroll
        for (int m = 0; m < 4; ++m)
#pragma unroll
            for (int nf = 0; nf < 4; ++nf)
                acc[m][nf] = __builtin_amdgcn_mfma_f32_16x16x32_bf16(af[m], bfv[nf], acc[m][nf], 0, 0, 0);
    }

#pragma unroll
    for (int m = 0; m < 4; ++m)
#pragma unroll
        for (int nf = 0; nf < 4; ++nf)
#pragma unroll
            for (int i = 0; i < 4; ++i) {
                int o = o0 + wr * 64 + m * 16 + g * 4 + i;
                int s = s0 + wc * 64 + nf * 16 + lc;
                out[((size_t)(b * 256 + o)) * 4096 + s] = acc[m][nf][i] + bp[o];
            }
}

extern "C" void kernel_launch(void* const* d_in, const int* in_sizes, int n_in,
                              void* d_out, int out_size, void* d_ws, size_t ws_size,
                              hipStream_t stream) {
    const float* x   = (const float*)d_in[0];
    const float* Wq  = (const float*)d_in[1];
    const float* bq  = (const float*)d_in[2];
    const float* Wkv = (const float*)d_in[3];
    const float* bkv = (const float*)d_in[4];
    const float* Wp  = (const float*)d_in[5];
    const float* bp  = (const float*)d_in[6];
    float* out = (float*)d_out;
    char* ws = (char*)d_ws;

    unsigned short* wb  = (unsigned short*)(ws);              // 768*256*2
    unsigned short* wpb = (unsigned short*)(ws + 393216);     // 256*256*2
    unsigned short* xT  = (unsigned short*)(ws + 524288);     // 8 MB
    unsigned short* qws = (unsigned short*)(ws + 8912896);
    unsigned short* kws = (unsigned short*)(ws + 17301504);
    unsigned short* vws = (unsigned short*)(ws + 25690112);
    unsigned short* att = (unsigned short*)(ws + 34078720);

    hipLaunchKernelGGL(k_conv_w, dim3(256), dim3(256), 0, stream, Wq, Wkv, Wp, wb, wpb);
    hipLaunchKernelGGL(k_xt, dim3(64, 4, 4), dim3(256), 0, stream, x, xT);
    hipLaunchKernelGGL(k_qkv, dim3(32, 6, 4), dim3(256), 0, stream, wb, xT, bq, bkv, qws, kws, vws);
    hipLaunchKernelGGL(k_attn, dim3(2048), dim3(256), 0, stream, qws, kws, vws, att);
    hipLaunchKernelGGL(k_proj, dim3(32, 2, 4), dim3(256), 0, stream, wpb, att, bp, out);
}

// Round 6
// 142.592 us; speedup vs baseline: 1.0787x; 1.0787x over previous
//
#include <hip/hip_runtime.h>

typedef __bf16 bf16x8 __attribute__((ext_vector_type(8)));
typedef float f32x4 __attribute__((ext_vector_type(4)));
typedef float f32x16 __attribute__((ext_vector_type(16)));

#define S_LEN 4096

__device__ __forceinline__ unsigned short f2bf(float f) {
    unsigned int u = __float_as_uint(f);
    u += 0x7fffu + ((u >> 16) & 1u);
    return (unsigned short)(u >> 16);
}

__device__ __forceinline__ unsigned int pk_bf16(float lo, float hi) {
    unsigned int r;
    asm("v_cvt_pk_bf16_f32 %0, %1, %2" : "=v"(r) : "v"(lo), "v"(hi));
    return r;
}

// ---------- weight conversion ----------
__global__ void k_conv_w(const float* __restrict__ Wq, const float* __restrict__ Wkv,
                         const float* __restrict__ Wp, unsigned short* __restrict__ wb,
                         unsigned short* __restrict__ wpb) {
    int stride = gridDim.x * blockDim.x;
    for (int i = blockIdx.x * blockDim.x + threadIdx.x; i < 262144; i += stride) {
        if (i < 65536)       wb[i]           = f2bf(Wq[i]);
        else if (i < 196608) wb[i]           = f2bf(Wkv[i - 65536]);
        else                 wpb[i - 196608] = f2bf(Wp[i - 196608]);
    }
}

// ---------- x (b,c,s) f32 -> xT (b,s,c) bf16 ----------
__global__ __launch_bounds__(256) void k_xt(const float* __restrict__ x, unsigned short* __restrict__ xT) {
    __shared__ unsigned short tile[64 * 80];
    const int b = blockIdx.z, c0 = blockIdx.y * 64, s0 = blockIdx.x * 64;
    const int tid = threadIdx.x;
#pragma unroll
    for (int ii = 0; ii < 4; ++ii) {
        int flat = ii * 256 + tid;
        int cr = flat >> 4, s4 = flat & 15;
        const float4 v = *(const float4*)(x + ((size_t)(b * 256 + c0 + cr)) * S_LEN + s0 + s4 * 4);
        tile[(s4 * 4 + 0) * 80 + cr] = f2bf(v.x);
        tile[(s4 * 4 + 1) * 80 + cr] = f2bf(v.y);
        tile[(s4 * 4 + 2) * 80 + cr] = f2bf(v.z);
        tile[(s4 * 4 + 3) * 80 + cr] = f2bf(v.w);
    }
    __syncthreads();
#pragma unroll
    for (int ii = 0; ii < 2; ++ii) {
        int flat = ii * 256 + tid;
        int sr = flat >> 3, ch = flat & 7;
        uint4 u = *(const uint4*)&tile[sr * 80 + ch * 8];
        *(uint4*)(xT + ((size_t)(b * 4096 + s0 + sr)) * 256 + c0 + ch * 8) = u;
    }
}

// ---------- QKV GEMM -> q (pre-scaled) / k [b][h][s][32], v [b][h][32][s] ----------
__global__ __launch_bounds__(256) void k_qkv(const unsigned short* __restrict__ wb,
                                             const unsigned short* __restrict__ xT,
                                             const float* __restrict__ bq,
                                             const float* __restrict__ bkv,
                                             unsigned short* __restrict__ qws,
                                             unsigned short* __restrict__ kws,
                                             unsigned short* __restrict__ vws) {
    __shared__ unsigned short As[128 * 32];
    __shared__ unsigned short Bs[128 * 32];
    const int b = blockIdx.z;
    const int o0 = blockIdx.y * 128, s0 = blockIdx.x * 128;
    const int tid = threadIdx.x;
    const int w = tid >> 6, l = tid & 63, g = l >> 4, lc = l & 15;
    const int wr = w >> 1, wc = w & 1;
    const unsigned short* xb = xT + (size_t)b * 4096 * 256;
    const float SM_C = 0.25505654458f;  // log2(e)/sqrt(32) folded into q

    f32x4 acc[4][4];
#pragma unroll
    for (int m = 0; m < 4; ++m)
#pragma unroll
        for (int nf = 0; nf < 4; ++nf) acc[m][nf] = (f32x4)(0.f);

    const int lrow = tid >> 1, lhalf = tid & 1;
    const int lsw0 = (lrow * 64 + lhalf * 32) ^ ((lrow & 7) << 4);
    const int lsw1 = (lrow * 64 + lhalf * 32 + 16) ^ ((lrow & 7) << 4);

    for (int kk = 0; kk < 8; ++kk) {
        const int c0 = kk * 32;
        __syncthreads();
        {
            const uint4* srcA = (const uint4*)(wb + (size_t)(o0 + lrow) * 256 + c0 + lhalf * 16);
            uint4 a0 = srcA[0], a1 = srcA[1];
            const uint4* srcB = (const uint4*)(xb + (size_t)(s0 + lrow) * 256 + c0 + lhalf * 16);
            uint4 b0 = srcB[0], b1 = srcB[1];
            *(uint4*)((char*)As + lsw0) = a0;
            *(uint4*)((char*)As + lsw1) = a1;
            *(uint4*)((char*)Bs + lsw0) = b0;
            *(uint4*)((char*)Bs + lsw1) = b1;
        }
        __syncthreads();
        bf16x8 af[4], bfv[4];
#pragma unroll
        for (int m = 0; m < 4; ++m) {
            int row = wr * 64 + m * 16 + lc;
            af[m] = *(const bf16x8*)((char*)As + ((row * 64 + g * 16) ^ ((row & 7) << 4)));
        }
#pragma unroll
        for (int nf = 0; nf < 4; ++nf) {
            int row = wc * 64 + nf * 16 + lc;
            bfv[nf] = *(const bf16x8*)((char*)Bs + ((row * 64 + g * 16) ^ ((row & 7) << 4)));
        }
#pragma unroll
        for (int m = 0; m < 4; ++m)
#pragma unroll
            for (int nf = 0; nf < 4; ++nf)
                acc[m][nf] = __builtin_amdgcn_mfma_f32_16x16x32_bf16(af[m], bfv[nf], acc[m][nf], 0, 0, 0);
    }

#pragma unroll
    for (int m = 0; m < 4; ++m)
#pragma unroll
        for (int nf = 0; nf < 4; ++nf)
#pragma unroll
            for (int i = 0; i < 4; ++i) {
                int o = o0 + wr * 64 + m * 16 + g * 4 + i;
                int s = s0 + wc * 64 + nf * 16 + lc;
                if (o < 256) {
                    int h = o >> 5, d = o & 31;
                    qws[(((size_t)(b * 8 + h)) * 4096 + s) * 32 + d] = f2bf((acc[m][nf][i] + bq[o]) * SM_C);
                } else if (o < 512) {
                    int oo = o - 256, h = oo >> 5, d = oo & 31;
                    kws[(((size_t)(b * 8 + h)) * 4096 + s) * 32 + d] = f2bf(acc[m][nf][i] + bkv[o - 256]);
                } else {
                    int oo = o - 512, h = oo >> 5, d = oo & 31;
                    vws[(((size_t)(b * 8 + h)) * 32 + d) * 4096 + s] = f2bf(acc[m][nf][i] + bkv[o - 256]);
                }
            }
}

// ---------- causal flash attention: 128-q block, 4 waves share LDS-staged K/V ----------
// LDS per buffer: K: 4 chunks (c = sel*2+hh) x [64 keys][16B] at stride 1056
//                 V: 8 chunks (c = sub*4+sel*2+hh) x [32 d][16B] at stride 544
#define KC_STRIDE 1056
#define VC_STRIDE 544
#define V_OFF     4224          // 4*1056
#define BUF_STRIDE 8576         // 4224 + 8*544 = 8576

__global__ __launch_bounds__(256) void k_attn(const unsigned short* __restrict__ qw,
                                              const unsigned short* __restrict__ kw,
                                              const unsigned short* __restrict__ vw,
                                              unsigned short* __restrict__ att) {
    __shared__ __align__(16) char smem[2 * BUF_STRIDE];

    const int tid = threadIdx.x;
    const int w = tid >> 6, l = tid & 63;
    const int lane31 = l & 31, hh = l >> 5;

    // XCD pinning (validated R4) + long/short q-tile pairing for balance.
    const int B = blockIdx.x;
    const int xcd = B & 7, j = B >> 3;             // j in [0,128)
    const int bh = xcd * 4 + (j & 3);
    const int u = j >> 2;                          // [0,32)
    const int qt = (u & 1) ? (31 - (u >> 1)) : (u >> 1);

    const int qsub = qt * 4 + w;                   // this wave's 32-row q-subtile index
    const int q = qt * 128 + w * 32 + lane31;
    const int nst = 2 * qt + 2;                    // 64-key rounds for this block

    const unsigned short* qw_bh = qw + (size_t)bh * 4096 * 32;
    const unsigned short* kw_bh = kw + (size_t)bh * 4096 * 32;
    const unsigned short* vw_bh = vw + (size_t)bh * 32 * 4096;

    const bf16x8 qf0 = *(const bf16x8*)(qw_bh + (size_t)q * 32 + hh * 8);
    const bf16x8 qf1 = *(const bf16x8*)(qw_bh + (size_t)q * 32 + hh * 8 + 16);

    // staging source (per thread, one 16B chunk of K and one of V per round)
    const unsigned short* ksrc = kw_bh + (tid >> 2) * 32 + (tid & 3) * 8;   // +2048/round
    const unsigned short* vsrc = vw_bh + (size_t)(tid >> 3) * 4096 + (tid & 7) * 8;  // +64/round
    const int kdst = (tid & 3) * KC_STRIDE + (tid >> 2) * 16;
    const int vdst = V_OFF + (tid & 7) * VC_STRIDE + (tid >> 3) * 16;

    f32x16 o, sums, zf;
#pragma unroll
    for (int r = 0; r < 16; ++r) { o[r] = 0.f; sums[r] = 0.f; zf[r] = 0.f; }

    union OU { unsigned int u[4]; bf16x8 v; };
    OU onesU;
#pragma unroll
    for (int jj = 0; jj < 4; ++jj) onesU.u[jj] = 0x3F803F80u;  // bf16 1.0 x2
    const bf16x8 ones = onesU.v;

    // prologue: stage round 0 into buf0
    {
        uint4 kreg = *(const uint4*)(ksrc);
        uint4 vreg = *(const uint4*)(vsrc);
        *(uint4*)(smem + kdst) = kreg;
        *(uint4*)(smem + vdst) = vreg;
    }

    int cur = 0;
    for (int st = 0; st < nst; ++st) {
        // issue next round's loads early (latency hides under compute)
        uint4 kreg, vreg;
        const bool pf = (st + 1 < nst);
        if (pf) {
            kreg = *(const uint4*)(ksrc + (size_t)(st + 1) * 2048);
            vreg = *(const uint4*)(vsrc + (size_t)(st + 1) * 64);
        }
        __syncthreads();   // buf[cur] fully written; buf[cur^1] reads (round st-1) done

        const char* kbuf = smem + cur * BUF_STRIDE;
        const char* vbuf = kbuf + V_OFF;

#pragma unroll
        for (int sub = 0; sub < 2; ++sub) {
            const int ksub = 2 * st + sub;
            if (ksub <= qsub) {
                bf16x8 kf0 = *(const bf16x8*)(kbuf + (hh)*KC_STRIDE + sub * 512 + lane31 * 16);
                bf16x8 kf1 = *(const bf16x8*)(kbuf + (2 + hh) * KC_STRIDE + sub * 512 + lane31 * 16);
                bf16x8 vf0 = *(const bf16x8*)(vbuf + (sub * 4 + hh) * VC_STRIDE + lane31 * 16);
                bf16x8 vf1 = *(const bf16x8*)(vbuf + (sub * 4 + 2 + hh) * VC_STRIDE + lane31 * 16);

                f32x16 s = __builtin_amdgcn_mfma_f32_32x32x16_bf16(kf0, qf0, zf, 0, 0, 0);
                s = __builtin_amdgcn_mfma_f32_32x32x16_bf16(kf1, qf1, s, 0, 0, 0);

                if (ksub == qsub) {
#pragma unroll
                    for (int r = 0; r < 16; ++r) {
                        int krel = (r & 3) + 8 * (r >> 2) + 4 * hh;
                        if (krel > lane31) s[r] = -1e30f;
                    }
                }

                float p[16];
#pragma unroll
                for (int r = 0; r < 16; ++r) p[r] = __builtin_amdgcn_exp2f(s[r]);

                unsigned int c00 = pk_bf16(p[0], p[1]),   c01 = pk_bf16(p[2], p[3]);
                unsigned int c10 = pk_bf16(p[4], p[5]),   c11 = pk_bf16(p[6], p[7]);
                unsigned int c20 = pk_bf16(p[8], p[9]),   c21 = pk_bf16(p[10], p[11]);
                unsigned int c30 = pk_bf16(p[12], p[13]), c31 = pk_bf16(p[14], p[15]);
                asm("v_permlane32_swap_b32 %0, %1" : "+v"(c00), "+v"(c10));
                asm("v_permlane32_swap_b32 %0, %1" : "+v"(c01), "+v"(c11));
                asm("v_permlane32_swap_b32 %0, %1" : "+v"(c20), "+v"(c30));
                asm("v_permlane32_swap_b32 %0, %1" : "+v"(c21), "+v"(c31));
                union U { uint4 u; bf16x8 v; };
                U pa0, pa1;
                pa0.u = make_uint4(c00, c01, c10, c11);
                pa1.u = make_uint4(c20, c21, c30, c31);

                sums = __builtin_amdgcn_mfma_f32_32x32x16_bf16(ones, pa0.v, sums, 0, 0, 0);
                sums = __builtin_amdgcn_mfma_f32_32x32x16_bf16(ones, pa1.v, sums, 0, 0, 0);
                o = __builtin_amdgcn_mfma_f32_32x32x16_bf16(vf0, pa0.v, o, 0, 0, 0);
                o = __builtin_amdgcn_mfma_f32_32x32x16_bf16(vf1, pa1.v, o, 0, 0, 0);
            }
        }

        if (pf) {
            char* nbuf = smem + (cur ^ 1) * BUF_STRIDE;
            *(uint4*)(nbuf + kdst) = kreg;
            *(uint4*)(nbuf + vdst) = vreg;
        }
        cur ^= 1;
    }

    const float inv = 1.0f / sums[0];
    unsigned int* dst = (unsigned int*)(att + (((size_t)(bh >> 3)) * 4096 + q) * 256 + (bh & 7) * 32);
#pragma unroll
    for (int jj = 0; jj < 8; ++jj) {
        unsigned int v = pk_bf16(o[2 * jj] * inv, o[2 * jj + 1] * inv);
        dst[(jj & 1) + 4 * (jj >> 1) + 2 * hh] = v;
    }
}

// ---------- output projection ----------
__global__ __launch_bounds__(256) void k_proj(const unsigned short* __restrict__ wpb,
                                              const unsigned short* __restrict__ att,
                                              const float* __restrict__ bp,
                                              float* __restrict__ out) {
    __shared__ unsigned short As[128 * 32];
    __shared__ unsigned short Bs[128 * 32];
    const int b = blockIdx.z;
    const int o0 = blockIdx.y * 128, s0 = blockIdx.x * 128;
    const int tid = threadIdx.x;
    const int w = tid >> 6, l = tid & 63, g = l >> 4, lc = l & 15;
    const int wr = w >> 1, wc = w & 1;
    const unsigned short* ab = att + (size_t)b * 4096 * 256;

    f32x4 acc[4][4];
#pragma unroll
    for (int m = 0; m < 4; ++m)
#pragma unroll
        for (int nf = 0; nf < 4; ++nf) acc[m][nf] = (f32x4)(0.f);

    const int lrow = tid >> 1, lhalf = tid & 1;
    const int lsw0 = (lrow * 64 + lhalf * 32) ^ ((lrow & 7) << 4);
    const int lsw1 = (lrow * 64 + lhalf * 32 + 16) ^ ((lrow & 7) << 4);

    for (int kk = 0; kk < 8; ++kk) {
        const int c0 = kk * 32;
        __syncthreads();
        {
            const uint4* srcA = (const uint4*)(wpb + (size_t)(o0 + lrow) * 256 + c0 + lhalf * 16);
            uint4 a0 = srcA[0], a1 = srcA[1];
            const uint4* srcB = (const uint4*)(ab + (size_t)(s0 + lrow) * 256 + c0 + lhalf * 16);
            uint4 b0 = srcB[0], b1 = srcB[1];
            *(uint4*)((char*)As + lsw0) = a0;
            *(uint4*)((char*)As + lsw1) = a1;
            *(uint4*)((char*)Bs + lsw0) = b0;
            *(uint4*)((char*)Bs + lsw1) = b1;
        }
        __syncthreads();
        bf16x8 af[4], bfv[4];
#pragma unroll
        for (int m = 0; m < 4; ++m) {
            int row = wr * 64 + m * 16 + lc;
            af[m] = *(const bf16x8*)((char*)As + ((row * 64 + g * 16) ^ ((row & 7) << 4)));
        }
#pragma unroll
        for (int nf = 0; nf < 4; ++nf) {
            int row = wc * 64 + nf * 16 + lc;
            bfv[nf] = *(const bf16x8*)((char*)Bs + ((row * 64 + g * 16) ^ ((row & 7) << 4)));
        }
#pragma unroll
        for (int m = 0; m < 4; ++m)
#pragma unroll
            for (int nf = 0; nf < 4; ++nf)
                acc[m][nf] = __builtin_amdgcn_mfma_f32_16x16x32_bf16(af[m], bfv[nf], acc[m][nf], 0, 0, 0);
    }

#pragma unroll
    for (int m = 0; m < 4; ++m)
#pragma unroll
        for (int nf = 0; nf < 4; ++nf)
#pragma unroll
            for (int i = 0; i < 4; ++i) {
                int o = o0 + wr * 64 + m * 16 + g * 4 + i;
                int s = s0 + wc * 64 + nf * 16 + lc;
                out[((size_t)(b * 256 + o)) * 4096 + s] = acc[m][nf][i] + bp[o];
            }
}

extern "C" void kernel_launch(void* const* d_in, const int* in_sizes, int n_in,
                              void* d_out, int out_size, void* d_ws, size_t ws_size,
                              hipStream_t stream) {
    const float* x   = (const float*)d_in[0];
    const float* Wq  = (const float*)d_in[1];
    const float* bq  = (const float*)d_in[2];
    const float* Wkv = (const float*)d_in[3];
    const float* bkv = (const float*)d_in[4];
    const float* Wp  = (const float*)d_in[5];
    const float* bp  = (const float*)d_in[6];
    float* out = (float*)d_out;
    char* ws = (char*)d_ws;

    unsigned short* wb  = (unsigned short*)(ws);              // 768*256*2
    unsigned short* wpb = (unsigned short*)(ws + 393216);     // 256*256*2
    unsigned short* xT  = (unsigned short*)(ws + 524288);     // 8 MB
    unsigned short* qws = (unsigned short*)(ws + 8912896);
    unsigned short* kws = (unsigned short*)(ws + 17301504);
    unsigned short* vws = (unsigned short*)(ws + 25690112);
    unsigned short* att = (unsigned short*)(ws + 34078720);

    hipLaunchKernelGGL(k_conv_w, dim3(256), dim3(256), 0, stream, Wq, Wkv, Wp, wb, wpb);
    hipLaunchKernelGGL(k_xt, dim3(64, 4, 4), dim3(256), 0, stream, x, xT);
    hipLaunchKernelGGL(k_qkv, dim3(32, 6, 4), dim3(256), 0, stream, wb, xT, bq, bkv, qws, kws, vws);
    hipLaunchKernelGGL(k_attn, dim3(1024), dim3(256), 0, stream, qws, kws, vws, att);
    hipLaunchKernelGGL(k_proj, dim3(32, 2, 4), dim3(256), 0, stream, wpb, att, bp, out);
}

// Round 7
// 126.939 us; speedup vs baseline: 1.2117x; 1.1233x over previous
//
#include <hip/hip_runtime.h>

typedef __bf16 bf16x8 __attribute__((ext_vector_type(8)));
typedef float f32x4 __attribute__((ext_vector_type(4)));
typedef float f32x16 __attribute__((ext_vector_type(16)));

#define S_LEN 4096

__device__ __forceinline__ unsigned short f2bf(float f) {
    unsigned int u = __float_as_uint(f);
    u += 0x7fffu + ((u >> 16) & 1u);
    return (unsigned short)(u >> 16);
}

__device__ __forceinline__ unsigned int pk_bf16(float lo, float hi) {
    unsigned int r;
    asm("v_cvt_pk_bf16_f32 %0, %1, %2" : "=v"(r) : "v"(lo), "v"(hi));
    return r;
}

// ---------- weight conversion ----------
__global__ void k_conv_w(const float* __restrict__ Wq, const float* __restrict__ Wkv,
                         const float* __restrict__ Wp, unsigned short* __restrict__ wb,
                         unsigned short* __restrict__ wpb) {
    int stride = gridDim.x * blockDim.x;
    for (int i = blockIdx.x * blockDim.x + threadIdx.x; i < 262144; i += stride) {
        if (i < 65536)       wb[i]           = f2bf(Wq[i]);
        else if (i < 196608) wb[i]           = f2bf(Wkv[i - 65536]);
        else                 wpb[i - 196608] = f2bf(Wp[i - 196608]);
    }
}

// ---------- x (b,c,s) f32 -> xT (b,s,c) bf16 ----------
__global__ __launch_bounds__(256) void k_xt(const float* __restrict__ x, unsigned short* __restrict__ xT) {
    __shared__ unsigned short tile[64 * 80];
    const int b = blockIdx.z, c0 = blockIdx.y * 64, s0 = blockIdx.x * 64;
    const int tid = threadIdx.x;
#pragma unroll
    for (int ii = 0; ii < 4; ++ii) {
        int flat = ii * 256 + tid;
        int cr = flat >> 4, s4 = flat & 15;
        const float4 v = *(const float4*)(x + ((size_t)(b * 256 + c0 + cr)) * S_LEN + s0 + s4 * 4);
        tile[(s4 * 4 + 0) * 80 + cr] = f2bf(v.x);
        tile[(s4 * 4 + 1) * 80 + cr] = f2bf(v.y);
        tile[(s4 * 4 + 2) * 80 + cr] = f2bf(v.z);
        tile[(s4 * 4 + 3) * 80 + cr] = f2bf(v.w);
    }
    __syncthreads();
#pragma unroll
    for (int ii = 0; ii < 2; ++ii) {
        int flat = ii * 256 + tid;
        int sr = flat >> 3, ch = flat & 7;
        uint4 u = *(const uint4*)&tile[sr * 80 + ch * 8];
        *(uint4*)(xT + ((size_t)(b * 4096 + s0 + sr)) * 256 + c0 + ch * 8) = u;
    }
}

// ---------- QKV GEMM -> q (pre-scaled) / k [b][h][s][32], v [b][h][32][s] ----------
__global__ __launch_bounds__(256) void k_qkv(const unsigned short* __restrict__ wb,
                                             const unsigned short* __restrict__ xT,
                                             const float* __restrict__ bq,
                                             const float* __restrict__ bkv,
                                             unsigned short* __restrict__ qws,
                                             unsigned short* __restrict__ kws,
                                             unsigned short* __restrict__ vws) {
    __shared__ unsigned short As[128 * 32];
    __shared__ unsigned short Bs[128 * 32];
    const int b = blockIdx.z;
    const int o0 = blockIdx.y * 128, s0 = blockIdx.x * 128;
    const int tid = threadIdx.x;
    const int w = tid >> 6, l = tid & 63, g = l >> 4, lc = l & 15;
    const int wr = w >> 1, wc = w & 1;
    const unsigned short* xb = xT + (size_t)b * 4096 * 256;
    const float SM_C = 0.25505654458f;  // log2(e)/sqrt(32) folded into q

    f32x4 acc[4][4];
#pragma unroll
    for (int m = 0; m < 4; ++m)
#pragma unroll
        for (int nf = 0; nf < 4; ++nf) acc[m][nf] = (f32x4)(0.f);

    const int lrow = tid >> 1, lhalf = tid & 1;
    const int lsw0 = (lrow * 64 + lhalf * 32) ^ ((lrow & 7) << 4);
    const int lsw1 = (lrow * 64 + lhalf * 32 + 16) ^ ((lrow & 7) << 4);

    for (int kk = 0; kk < 8; ++kk) {
        const int c0 = kk * 32;
        __syncthreads();
        {
            const uint4* srcA = (const uint4*)(wb + (size_t)(o0 + lrow) * 256 + c0 + lhalf * 16);
            uint4 a0 = srcA[0], a1 = srcA[1];
            const uint4* srcB = (const uint4*)(xb + (size_t)(s0 + lrow) * 256 + c0 + lhalf * 16);
            uint4 b0 = srcB[0], b1 = srcB[1];
            *(uint4*)((char*)As + lsw0) = a0;
            *(uint4*)((char*)As + lsw1) = a1;
            *(uint4*)((char*)Bs + lsw0) = b0;
            *(uint4*)((char*)Bs + lsw1) = b1;
        }
        __syncthreads();
        bf16x8 af[4], bfv[4];
#pragma unroll
        for (int m = 0; m < 4; ++m) {
            int row = wr * 64 + m * 16 + lc;
            af[m] = *(const bf16x8*)((char*)As + ((row * 64 + g * 16) ^ ((row & 7) << 4)));
        }
#pragma unroll
        for (int nf = 0; nf < 4; ++nf) {
            int row = wc * 64 + nf * 16 + lc;
            bfv[nf] = *(const bf16x8*)((char*)Bs + ((row * 64 + g * 16) ^ ((row & 7) << 4)));
        }
#pragma unroll
        for (int m = 0; m < 4; ++m)
#pragma unroll
            for (int nf = 0; nf < 4; ++nf)
                acc[m][nf] = __builtin_amdgcn_mfma_f32_16x16x32_bf16(af[m], bfv[nf], acc[m][nf], 0, 0, 0);
    }

#pragma unroll
    for (int m = 0; m < 4; ++m)
#pragma unroll
        for (int nf = 0; nf < 4; ++nf)
#pragma unroll
            for (int i = 0; i < 4; ++i) {
                int o = o0 + wr * 64 + m * 16 + g * 4 + i;
                int s = s0 + wc * 64 + nf * 16 + lc;
                if (o < 256) {
                    int h = o >> 5, d = o & 31;
                    qws[(((size_t)(b * 8 + h)) * 4096 + s) * 32 + d] = f2bf((acc[m][nf][i] + bq[o]) * SM_C);
                } else if (o < 512) {
                    int oo = o - 256, h = oo >> 5, d = oo & 31;
                    kws[(((size_t)(b * 8 + h)) * 4096 + s) * 32 + d] = f2bf(acc[m][nf][i] + bkv[o - 256]);
                } else {
                    int oo = o - 512, h = oo >> 5, d = oo & 31;
                    vws[(((size_t)(b * 8 + h)) * 32 + d) * 4096 + s] = f2bf(acc[m][nf][i] + bkv[o - 256]);
                }
            }
}

// ---------- causal flash attention: 64-q block, 2 waves share LDS-staged K/V ----------
// LDS per buffer: K: 4 chunks (c = sel*2+hh) x [64 keys][16B] at stride 1056
//                 V: 8 chunks (c = sub*4+sel*2+hh) x [32 d][16B] at stride 544
#define KC_STRIDE 1056
#define VC_STRIDE 544
#define V_OFF     4224          // 4*1056
#define BUF_STRIDE 8576         // 4224 + 8*544

__device__ __forceinline__ void attn_sub(const char* __restrict__ kbuf, const char* __restrict__ vbuf,
                                         int sub, bf16x8 qf0, bf16x8 qf1, const f32x16& zf, bf16x8 ones,
                                         int lane31, int hh, bool domask,
                                         f32x16& o, f32x16& sums) {
    bf16x8 kf0 = *(const bf16x8*)(kbuf + hh * KC_STRIDE + sub * 512 + lane31 * 16);
    bf16x8 kf1 = *(const bf16x8*)(kbuf + (2 + hh) * KC_STRIDE + sub * 512 + lane31 * 16);
    bf16x8 vf0 = *(const bf16x8*)(vbuf + (sub * 4 + hh) * VC_STRIDE + lane31 * 16);
    bf16x8 vf1 = *(const bf16x8*)(vbuf + (sub * 4 + 2 + hh) * VC_STRIDE + lane31 * 16);

    f32x16 s = __builtin_amdgcn_mfma_f32_32x32x16_bf16(kf0, qf0, zf, 0, 0, 0);
    s = __builtin_amdgcn_mfma_f32_32x32x16_bf16(kf1, qf1, s, 0, 0, 0);

    if (domask) {
#pragma unroll
        for (int r = 0; r < 16; ++r) {
            int krel = (r & 3) + 8 * (r >> 2) + 4 * hh;
            if (krel > lane31) s[r] = -1e30f;
        }
    }

    float p[16];
#pragma unroll
    for (int r = 0; r < 16; ++r) p[r] = __builtin_amdgcn_exp2f(s[r]);

    unsigned int c00 = pk_bf16(p[0], p[1]),   c01 = pk_bf16(p[2], p[3]);
    unsigned int c10 = pk_bf16(p[4], p[5]),   c11 = pk_bf16(p[6], p[7]);
    unsigned int c20 = pk_bf16(p[8], p[9]),   c21 = pk_bf16(p[10], p[11]);
    unsigned int c30 = pk_bf16(p[12], p[13]), c31 = pk_bf16(p[14], p[15]);
    asm("v_permlane32_swap_b32 %0, %1" : "+v"(c00), "+v"(c10));
    asm("v_permlane32_swap_b32 %0, %1" : "+v"(c01), "+v"(c11));
    asm("v_permlane32_swap_b32 %0, %1" : "+v"(c20), "+v"(c30));
    asm("v_permlane32_swap_b32 %0, %1" : "+v"(c21), "+v"(c31));
    union U { uint4 u; bf16x8 v; };
    U pa0, pa1;
    pa0.u = make_uint4(c00, c01, c10, c11);
    pa1.u = make_uint4(c20, c21, c30, c31);

    sums = __builtin_amdgcn_mfma_f32_32x32x16_bf16(ones, pa0.v, sums, 0, 0, 0);
    sums = __builtin_amdgcn_mfma_f32_32x32x16_bf16(ones, pa1.v, sums, 0, 0, 0);
    o = __builtin_amdgcn_mfma_f32_32x32x16_bf16(vf0, pa0.v, o, 0, 0, 0);
    o = __builtin_amdgcn_mfma_f32_32x32x16_bf16(vf1, pa1.v, o, 0, 0, 0);
}

__global__ __launch_bounds__(128) void k_attn(const unsigned short* __restrict__ qw,
                                              const unsigned short* __restrict__ kw,
                                              const unsigned short* __restrict__ vw,
                                              unsigned short* __restrict__ att) {
    __shared__ __align__(16) char smem[2 * BUF_STRIDE];

    const int tid = threadIdx.x;
    const int w = tid >> 6, l = tid & 63;
    const int lane31 = l & 31, hh = l >> 5;

    // XCD pinning (validated R4) + longest-first ordering to shrink the drain tail.
    const int B = blockIdx.x;
    const int xcd = B & 7, idx = B >> 3;           // idx in [0,256)
    const int bh = xcd * 4 + (idx & 3);
    const int m = 63 - (idx >> 2);                 // q half-tile index, longest first

    const int q = m * 64 + w * 32 + lane31;

    const unsigned short* qw_bh = qw + (size_t)bh * 4096 * 32;
    const unsigned short* kw_bh = kw + (size_t)bh * 4096 * 32;
    const unsigned short* vw_bh = vw + (size_t)bh * 32 * 4096;

    const bf16x8 qf0 = *(const bf16x8*)(qw_bh + (size_t)q * 32 + hh * 8);
    const bf16x8 qf1 = *(const bf16x8*)(qw_bh + (size_t)q * 32 + hh * 8 + 16);

    // staging: 128 threads x 4 x 16B chunks per 64-key round
    const unsigned short* ksrc = kw_bh + (tid >> 1) * 32 + (tid & 1) * 8;
    const unsigned short* vsrc = vw_bh + (size_t)(tid >> 2) * 4096 + (tid & 3) * 8;
    const int kdst0 = (tid & 1) * KC_STRIDE + (tid >> 1) * 16;
    const int kdst1 = kdst0 + 2 * KC_STRIDE;
    const int vdst0 = V_OFF + (tid & 3) * VC_STRIDE + (tid >> 2) * 16;
    const int vdst1 = vdst0 + 4 * VC_STRIDE;

    f32x16 o, sums, zf;
#pragma unroll
    for (int r = 0; r < 16; ++r) { o[r] = 0.f; sums[r] = 0.f; zf[r] = 0.f; }

    union OU { unsigned int u[4]; bf16x8 v; };
    OU onesU;
#pragma unroll
    for (int jj = 0; jj < 4; ++jj) onesU.u[jj] = 0x3F803F80u;  // bf16 1.0 x2
    const bf16x8 ones = onesU.v;

    // prologue: stage round 0 into buf0
    {
        uint4 k0 = *(const uint4*)(ksrc);
        uint4 k1 = *(const uint4*)(ksrc + 16);
        uint4 v0 = *(const uint4*)(vsrc);
        uint4 v1 = *(const uint4*)(vsrc + 32);
        *(uint4*)(smem + kdst0) = k0;
        *(uint4*)(smem + kdst1) = k1;
        *(uint4*)(smem + vdst0) = v0;
        *(uint4*)(smem + vdst1) = v1;
    }

    int cur = 0;
    // main loop: rounds 0..m-1 are causally FULL for both waves -> branch-free
    for (int st = 0; st < m; ++st) {
        // issue next round's loads early
        const unsigned short* kp = ksrc + (size_t)(st + 1) * 2048;
        const unsigned short* vp = vsrc + (size_t)(st + 1) * 64;
        uint4 k0 = *(const uint4*)(kp);
        uint4 k1 = *(const uint4*)(kp + 16);
        uint4 v0 = *(const uint4*)(vp);
        uint4 v1 = *(const uint4*)(vp + 32);

        __syncthreads();
        const char* kbuf = smem + cur * BUF_STRIDE;
        const char* vbuf = kbuf + V_OFF;
        attn_sub(kbuf, vbuf, 0, qf0, qf1, zf, ones, lane31, hh, false, o, sums);
        attn_sub(kbuf, vbuf, 1, qf0, qf1, zf, ones, lane31, hh, false, o, sums);

        char* nbuf = smem + (cur ^ 1) * BUF_STRIDE;
        *(uint4*)(nbuf + kdst0) = k0;
        *(uint4*)(nbuf + kdst1) = k1;
        *(uint4*)(nbuf + vdst0) = v0;
        *(uint4*)(nbuf + vdst1) = v1;
        cur ^= 1;
    }

    __syncthreads();
    // epilogue: round m (diagonal). sub0: both waves, mask only wave 0.
    //           sub1: wave 1 only, always masked.
    {
        const char* kbuf = smem + cur * BUF_STRIDE;
        const char* vbuf = kbuf + V_OFF;
        attn_sub(kbuf, vbuf, 0, qf0, qf1, zf, ones, lane31, hh, (w == 0), o, sums);
        if (w == 1)
            attn_sub(kbuf, vbuf, 1, qf0, qf1, zf, ones, lane31, hh, true, o, sums);
    }

    const float inv = 1.0f / sums[0];
    unsigned int* dst = (unsigned int*)(att + (((size_t)(bh >> 3)) * 4096 + q) * 256 + (bh & 7) * 32);
#pragma unroll
    for (int jj = 0; jj < 8; ++jj) {
        unsigned int v = pk_bf16(o[2 * jj] * inv, o[2 * jj + 1] * inv);
        dst[(jj & 1) + 4 * (jj >> 1) + 2 * hh] = v;
    }
}

// ---------- output projection ----------
__global__ __launch_bounds__(256) void k_proj(const unsigned short* __restrict__ wpb,
                                              const unsigned short* __restrict__ att,
                                              const float* __restrict__ bp,
                                              float* __restrict__ out) {
    __shared__ unsigned short As[128 * 32];
    __shared__ unsigned short Bs[128 * 32];
    const int b = blockIdx.z;
    const int o0 = blockIdx.y * 128, s0 = blockIdx.x * 128;
    const int tid = threadIdx.x;
    const int w = tid >> 6, l = tid & 63, g = l >> 4, lc = l & 15;
    const int wr = w >> 1, wc = w & 1;
    const unsigned short* ab = att + (size_t)b * 4096 * 256;

    f32x4 acc[4][4];
#pragma unroll
    for (int m = 0; m < 4; ++m)
#pragma unroll
        for (int nf = 0; nf < 4; ++nf) acc[m][nf] = (f32x4)(0.f);

    const int lrow = tid >> 1, lhalf = tid & 1;
    const int lsw0 = (lrow * 64 + lhalf * 32) ^ ((lrow & 7) << 4);
    const int lsw1 = (lrow * 64 + lhalf * 32 + 16) ^ ((lrow & 7) << 4);

    for (int kk = 0; kk < 8; ++kk) {
        const int c0 = kk * 32;
        __syncthreads();
        {
            const uint4* srcA = (const uint4*)(wpb + (size_t)(o0 + lrow) * 256 + c0 + lhalf * 16);
            uint4 a0 = srcA[0], a1 = srcA[1];
            const uint4* srcB = (const uint4*)(ab + (size_t)(s0 + lrow) * 256 + c0 + lhalf * 16);
            uint4 b0 = srcB[0], b1 = srcB[1];
            *(uint4*)((char*)As + lsw0) = a0;
            *(uint4*)((char*)As + lsw1) = a1;
            *(uint4*)((char*)Bs + lsw0) = b0;
            *(uint4*)((char*)Bs + lsw1) = b1;
        }
        __syncthreads();
        bf16x8 af[4], bfv[4];
#pragma unroll
        for (int m = 0; m < 4; ++m) {
            int row = wr * 64 + m * 16 + lc;
            af[m] = *(const bf16x8*)((char*)As + ((row * 64 + g * 16) ^ ((row & 7) << 4)));
        }
#pragma unroll
        for (int nf = 0; nf < 4; ++nf) {
            int row = wc * 64 + nf * 16 + lc;
            bfv[nf] = *(const bf16x8*)((char*)Bs + ((row * 64 + g * 16) ^ ((row & 7) << 4)));
        }
#pragma unroll
        for (int m = 0; m < 4; ++m)
#pragma unroll
            for (int nf = 0; nf < 4; ++nf)
                acc[m][nf] = __builtin_amdgcn_mfma_f32_16x16x32_bf16(af[m], bfv[nf], acc[m][nf], 0, 0, 0);
    }

#pragma unroll
    for (int m = 0; m < 4; ++m)
#pragma unroll
        for (int nf = 0; nf < 4; ++nf)
#pragma unroll
            for (int i = 0; i < 4; ++i) {
                int o = o0 + wr * 64 + m * 16 + g * 4 + i;
                int s = s0 + wc * 64 + nf * 16 + lc;
                out[((size_t)(b * 256 + o)) * 4096 + s] = acc[m][nf][i] + bp[o];
            }
}

extern "C" void kernel_launch(void* const* d_in, const int* in_sizes, int n_in,
                              void* d_out, int out_size, void* d_ws, size_t ws_size,
                              hipStream_t stream) {
    const float* x   = (const float*)d_in[0];
    const float* Wq  = (const float*)d_in[1];
    const float* bq  = (const float*)d_in[2];
    const float* Wkv = (const float*)d_in[3];
    const float* bkv = (const float*)d_in[4];
    const float* Wp  = (const float*)d_in[5];
    const float* bp  = (const float*)d_in[6];
    float* out = (float*)d_out;
    char* ws = (char*)d_ws;

    unsigned short* wb  = (unsigned short*)(ws);              // 768*256*2
    unsigned short* wpb = (unsigned short*)(ws + 393216);     // 256*256*2
    unsigned short* xT  = (unsigned short*)(ws + 524288);     // 8 MB
    unsigned short* qws = (unsigned short*)(ws + 8912896);
    unsigned short* kws = (unsigned short*)(ws + 17301504);
    unsigned short* vws = (unsigned short*)(ws + 25690112);
    unsigned short* att = (unsigned short*)(ws + 34078720);

    hipLaunchKernelGGL(k_conv_w, dim3(256), dim3(256), 0, stream, Wq, Wkv, Wp, wb, wpb);
    hipLaunchKernelGGL(k_xt, dim3(64, 4, 4), dim3(256), 0, stream, x, xT);
    hipLaunchKernelGGL(k_qkv, dim3(32, 6, 4), dim3(256), 0, stream, wb, xT, bq, bkv, qws, kws, vws);
    hipLaunchKernelGGL(k_attn, dim3(2048), dim3(128), 0, stream, qws, kws, vws, att);
    hipLaunchKernelGGL(k_proj, dim3(32, 2, 4), dim3(256), 0, stream, wpb, att, bp, out);
}

// Round 8
// 121.580 us; speedup vs baseline: 1.2651x; 1.0441x over previous
//
#include <hip/hip_runtime.h>

typedef __bf16 bf16x8 __attribute__((ext_vector_type(8)));
typedef float f32x4 __attribute__((ext_vector_type(4)));
typedef float f32x16 __attribute__((ext_vector_type(16)));

#define S_LEN 4096

__device__ __forceinline__ unsigned short f2bf(float f) {
    unsigned int u = __float_as_uint(f);
    u += 0x7fffu + ((u >> 16) & 1u);
    return (unsigned short)(u >> 16);
}

__device__ __forceinline__ unsigned int pk_bf16(float lo, float hi) {
    unsigned int r;
    asm("v_cvt_pk_bf16_f32 %0, %1, %2" : "=v"(r) : "v"(lo), "v"(hi));
    return r;
}

// ---------- x (b,c,s) f32 -> xT (b,s,c) bf16 ; z==4 slice does weight conversion ----------
__global__ __launch_bounds__(256) void k_xt(const float* __restrict__ x, unsigned short* __restrict__ xT,
                                            const float* __restrict__ Wq, const float* __restrict__ Wkv,
                                            const float* __restrict__ Wp, unsigned short* __restrict__ wb,
                                            unsigned short* __restrict__ wpb) {
    __shared__ unsigned short tile[64 * 80];
    const int tid = threadIdx.x;
    if (blockIdx.z == 4) {
        // weight conversion: 262144 elements over 256 blocks x 256 threads x 4
        const int bi = blockIdx.x + 64 * blockIdx.y;
        for (int i = bi * 256 + tid; i < 262144; i += 65536) {
            if (i < 65536)       wb[i]           = f2bf(Wq[i]);
            else if (i < 196608) wb[i]           = f2bf(Wkv[i - 65536]);
            else                 wpb[i - 196608] = f2bf(Wp[i - 196608]);
        }
        return;
    }
    const int b = blockIdx.z, c0 = blockIdx.y * 64, s0 = blockIdx.x * 64;
#pragma unroll
    for (int ii = 0; ii < 4; ++ii) {
        int flat = ii * 256 + tid;
        int cr = flat >> 4, s4 = flat & 15;
        const float4 v = *(const float4*)(x + ((size_t)(b * 256 + c0 + cr)) * S_LEN + s0 + s4 * 4);
        tile[(s4 * 4 + 0) * 80 + cr] = f2bf(v.x);
        tile[(s4 * 4 + 1) * 80 + cr] = f2bf(v.y);
        tile[(s4 * 4 + 2) * 80 + cr] = f2bf(v.z);
        tile[(s4 * 4 + 3) * 80 + cr] = f2bf(v.w);
    }
    __syncthreads();
#pragma unroll
    for (int ii = 0; ii < 2; ++ii) {
        int flat = ii * 256 + tid;
        int sr = flat >> 3, ch = flat & 7;
        uint4 u = *(const uint4*)&tile[sr * 80 + ch * 8];
        *(uint4*)(xT + ((size_t)(b * 4096 + s0 + sr)) * 256 + c0 + ch * 8) = u;
    }
}

// ---------- QKV GEMM -> q (pre-scaled) / k [b][h][s][32], v [b][h][32][s] ----------
__global__ __launch_bounds__(256) void k_qkv(const unsigned short* __restrict__ wb,
                                             const unsigned short* __restrict__ xT,
                                             const float* __restrict__ bq,
                                             const float* __restrict__ bkv,
                                             unsigned short* __restrict__ qws,
                                             unsigned short* __restrict__ kws,
                                             unsigned short* __restrict__ vws) {
    __shared__ unsigned short As[128 * 32];
    __shared__ unsigned short Bs[128 * 32];
    const int b = blockIdx.z;
    const int o0 = blockIdx.y * 128, s0 = blockIdx.x * 128;
    const int tid = threadIdx.x;
    const int w = tid >> 6, l = tid & 63, g = l >> 4, lc = l & 15;
    const int wr = w >> 1, wc = w & 1;
    const unsigned short* xb = xT + (size_t)b * 4096 * 256;
    const float SM_C = 0.25505654458f;  // log2(e)/sqrt(32) folded into q

    f32x4 acc[4][4];
#pragma unroll
    for (int m = 0; m < 4; ++m)
#pragma unroll
        for (int nf = 0; nf < 4; ++nf) acc[m][nf] = (f32x4)(0.f);

    const int lrow = tid >> 1, lhalf = tid & 1;
    const int lsw0 = (lrow * 64 + lhalf * 32) ^ ((lrow & 7) << 4);
    const int lsw1 = (lrow * 64 + lhalf * 32 + 16) ^ ((lrow & 7) << 4);

    for (int kk = 0; kk < 8; ++kk) {
        const int c0 = kk * 32;
        __syncthreads();
        {
            const uint4* srcA = (const uint4*)(wb + (size_t)(o0 + lrow) * 256 + c0 + lhalf * 16);
            uint4 a0 = srcA[0], a1 = srcA[1];
            const uint4* srcB = (const uint4*)(xb + (size_t)(s0 + lrow) * 256 + c0 + lhalf * 16);
            uint4 b0 = srcB[0], b1 = srcB[1];
            *(uint4*)((char*)As + lsw0) = a0;
            *(uint4*)((char*)As + lsw1) = a1;
            *(uint4*)((char*)Bs + lsw0) = b0;
            *(uint4*)((char*)Bs + lsw1) = b1;
        }
        __syncthreads();
        bf16x8 af[4], bfv[4];
#pragma unroll
        for (int m = 0; m < 4; ++m) {
            int row = wr * 64 + m * 16 + lc;
            af[m] = *(const bf16x8*)((char*)As + ((row * 64 + g * 16) ^ ((row & 7) << 4)));
        }
#pragma unroll
        for (int nf = 0; nf < 4; ++nf) {
            int row = wc * 64 + nf * 16 + lc;
            bfv[nf] = *(const bf16x8*)((char*)Bs + ((row * 64 + g * 16) ^ ((row & 7) << 4)));
        }
#pragma unroll
        for (int m = 0; m < 4; ++m)
#pragma unroll
            for (int nf = 0; nf < 4; ++nf)
                acc[m][nf] = __builtin_amdgcn_mfma_f32_16x16x32_bf16(af[m], bfv[nf], acc[m][nf], 0, 0, 0);
    }

#pragma unroll
    for (int m = 0; m < 4; ++m)
#pragma unroll
        for (int nf = 0; nf < 4; ++nf)
#pragma unroll
            for (int i = 0; i < 4; ++i) {
                int o = o0 + wr * 64 + m * 16 + g * 4 + i;
                int s = s0 + wc * 64 + nf * 16 + lc;
                if (o < 256) {
                    int h = o >> 5, d = o & 31;
                    qws[(((size_t)(b * 8 + h)) * 4096 + s) * 32 + d] = f2bf((acc[m][nf][i] + bq[o]) * SM_C);
                } else if (o < 512) {
                    int oo = o - 256, h = oo >> 5, d = oo & 31;
                    kws[(((size_t)(b * 8 + h)) * 4096 + s) * 32 + d] = f2bf(acc[m][nf][i] + bkv[o - 256]);
                } else {
                    int oo = o - 512, h = oo >> 5, d = oo & 31;
                    vws[(((size_t)(b * 8 + h)) * 32 + d) * 4096 + s] = f2bf(acc[m][nf][i] + bkv[o - 256]);
                }
            }
}

// ---------- causal flash attention: 64-q block (2 waves), K direct from global,
// ---------- V LDS-dbuf, 128-key rounds (4 sub-chains of ILP per wave) ----------
#define VC_STRIDE 544
#define NCHUNK 16
#define BUF_STRIDE (NCHUNK * VC_STRIDE)   // 8704

__device__ __forceinline__ void attn_sub(const unsigned short* __restrict__ kw_bh, int key0,
                                         const char* __restrict__ vbuf, int c,
                                         bf16x8 qf0, bf16x8 qf1, const f32x16& zf, bf16x8 ones,
                                         int lane31, int hh, bool domask,
                                         f32x16& o, f32x16& sums) {
    const unsigned short* kp = kw_bh + (size_t)(key0 + lane31) * 32 + hh * 8;
    bf16x8 kf0 = *(const bf16x8*)(kp);
    bf16x8 kf1 = *(const bf16x8*)(kp + 16);
    bf16x8 vf0 = *(const bf16x8*)(vbuf + (c * 4 + hh) * VC_STRIDE + lane31 * 16);
    bf16x8 vf1 = *(const bf16x8*)(vbuf + (c * 4 + 2 + hh) * VC_STRIDE + lane31 * 16);

    f32x16 s = __builtin_amdgcn_mfma_f32_32x32x16_bf16(kf0, qf0, zf, 0, 0, 0);
    s = __builtin_amdgcn_mfma_f32_32x32x16_bf16(kf1, qf1, s, 0, 0, 0);

    if (domask) {
#pragma unroll
        for (int r = 0; r < 16; ++r) {
            int krel = (r & 3) + 8 * (r >> 2) + 4 * hh;
            if (krel > lane31) s[r] = -1e30f;
        }
    }

    float p[16];
#pragma unroll
    for (int r = 0; r < 16; ++r) p[r] = __builtin_amdgcn_exp2f(s[r]);

    unsigned int c00 = pk_bf16(p[0], p[1]),   c01 = pk_bf16(p[2], p[3]);
    unsigned int c10 = pk_bf16(p[4], p[5]),   c11 = pk_bf16(p[6], p[7]);
    unsigned int c20 = pk_bf16(p[8], p[9]),   c21 = pk_bf16(p[10], p[11]);
    unsigned int c30 = pk_bf16(p[12], p[13]), c31 = pk_bf16(p[14], p[15]);
    asm("v_permlane32_swap_b32 %0, %1" : "+v"(c00), "+v"(c10));
    asm("v_permlane32_swap_b32 %0, %1" : "+v"(c01), "+v"(c11));
    asm("v_permlane32_swap_b32 %0, %1" : "+v"(c20), "+v"(c30));
    asm("v_permlane32_swap_b32 %0, %1" : "+v"(c21), "+v"(c31));
    union U { uint4 u; bf16x8 v; };
    U pa0, pa1;
    pa0.u = make_uint4(c00, c01, c10, c11);
    pa1.u = make_uint4(c20, c21, c30, c31);

    sums = __builtin_amdgcn_mfma_f32_32x32x16_bf16(ones, pa0.v, sums, 0, 0, 0);
    sums = __builtin_amdgcn_mfma_f32_32x32x16_bf16(ones, pa1.v, sums, 0, 0, 0);
    o = __builtin_amdgcn_mfma_f32_32x32x16_bf16(vf0, pa0.v, o, 0, 0, 0);
    o = __builtin_amdgcn_mfma_f32_32x32x16_bf16(vf1, pa1.v, o, 0, 0, 0);
}

__global__ __launch_bounds__(128, 4) void k_attn(const unsigned short* __restrict__ qw,
                                                 const unsigned short* __restrict__ kw,
                                                 const unsigned short* __restrict__ vw,
                                                 unsigned short* __restrict__ att) {
    __shared__ __align__(16) char smem[2 * BUF_STRIDE];

    const int tid = threadIdx.x;
    const int w = tid >> 6, l = tid & 63;
    const int lane31 = l & 31, hh = l >> 5;

    // XCD pinning (validated R4) + longest-first ordering.
    const int B = blockIdx.x;
    const int xcd = B & 7, idx = B >> 3;           // idx in [0,256)
    const int bh = xcd * 4 + (idx & 3);
    const int m = 63 - (idx >> 2);                 // 64-q tile index, longest first

    const int q = m * 64 + w * 32 + lane31;
    const int R = (m + 2) >> 1;                    // 128-key rounds
    const int smax = 2 * m + w;                    // this wave's last (diagonal) 32-key sub

    const unsigned short* qw_bh = qw + (size_t)bh * 4096 * 32;
    const unsigned short* kw_bh = kw + (size_t)bh * 4096 * 32;
    const unsigned short* vw_bh = vw + (size_t)bh * 32 * 4096;

    const bf16x8 qf0 = *(const bf16x8*)(qw_bh + (size_t)q * 32 + hh * 8);
    const bf16x8 qf1 = *(const bf16x8*)(qw_bh + (size_t)q * 32 + hh * 8 + 16);

    // V staging: 128 threads x 4 x 16B per 128-key round.
    // thread covers oct = tid&15 (8-key group), rows (tid>>4)+8j, j=0..3
    const unsigned short* vsrc0 = vw_bh + (size_t)(tid >> 4) * 4096 + (tid & 15) * 8;
    const int vdst0 = (tid & 15) * VC_STRIDE + (tid >> 4) * 16;

    f32x16 o, sums, zf;
#pragma unroll
    for (int r = 0; r < 16; ++r) { o[r] = 0.f; sums[r] = 0.f; zf[r] = 0.f; }

    union OU { unsigned int u[4]; bf16x8 v; };
    OU onesU;
#pragma unroll
    for (int jj = 0; jj < 4; ++jj) onesU.u[jj] = 0x3F803F80u;  // bf16 1.0 x2
    const bf16x8 ones = onesU.v;

    // prologue: stage round 0 into buf0
    {
        uint4 v0 = *(const uint4*)(vsrc0);
        uint4 v1 = *(const uint4*)(vsrc0 + 32768);
        uint4 v2 = *(const uint4*)(vsrc0 + 65536);
        uint4 v3 = *(const uint4*)(vsrc0 + 98304);
        *(uint4*)(smem + vdst0)       = v0;
        *(uint4*)(smem + vdst0 + 128) = v1;
        *(uint4*)(smem + vdst0 + 256) = v2;
        *(uint4*)(smem + vdst0 + 384) = v3;
    }

    int cur = 0;
    // main rounds: all 4 subs causally full for both waves
    for (int r = 0; r < R - 1; ++r) {
        const unsigned short* vp = vsrc0 + (size_t)(r + 1) * 128;
        uint4 v0 = *(const uint4*)(vp);
        uint4 v1 = *(const uint4*)(vp + 32768);
        uint4 v2 = *(const uint4*)(vp + 65536);
        uint4 v3 = *(const uint4*)(vp + 98304);

        __syncthreads();
        const char* vbuf = smem + cur * BUF_STRIDE;
        const int k0 = r * 128;
        attn_sub(kw_bh, k0,      vbuf, 0, qf0, qf1, zf, ones, lane31, hh, false, o, sums);
        attn_sub(kw_bh, k0 + 32, vbuf, 1, qf0, qf1, zf, ones, lane31, hh, false, o, sums);
        attn_sub(kw_bh, k0 + 64, vbuf, 2, qf0, qf1, zf, ones, lane31, hh, false, o, sums);
        attn_sub(kw_bh, k0 + 96, vbuf, 3, qf0, qf1, zf, ones, lane31, hh, false, o, sums);

        char* nbuf = smem + (cur ^ 1) * BUF_STRIDE;
        *(uint4*)(nbuf + vdst0)       = v0;
        *(uint4*)(nbuf + vdst0 + 128) = v1;
        *(uint4*)(nbuf + vdst0 + 256) = v2;
        *(uint4*)(nbuf + vdst0 + 384) = v3;
        cur ^= 1;
    }

    __syncthreads();
    // last round: subs 4(R-1) .. smax, wave-uniform predicates, diagonal mask at smax
    {
        const char* vbuf = smem + cur * BUF_STRIDE;
        const int k0 = (R - 1) * 128;
        const int sbase = 4 * (R - 1);
#pragma unroll
        for (int c = 0; c < 4; ++c) {
            const int s = sbase + c;
            if (s <= smax)
                attn_sub(kw_bh, k0 + c * 32, vbuf, c, qf0, qf1, zf, ones, lane31, hh, s == smax, o, sums);
        }
    }

    const float inv = 1.0f / sums[0];
    unsigned int* dst = (unsigned int*)(att + (((size_t)(bh >> 3)) * 4096 + q) * 256 + (bh & 7) * 32);
#pragma unroll
    for (int jj = 0; jj < 8; ++jj) {
        unsigned int v = pk_bf16(o[2 * jj] * inv, o[2 * jj + 1] * inv);
        dst[(jj & 1) + 4 * (jj >> 1) + 2 * hh] = v;
    }
}

// ---------- output projection ----------
__global__ __launch_bounds__(256) void k_proj(const unsigned short* __restrict__ wpb,
                                              const unsigned short* __restrict__ att,
                                              const float* __restrict__ bp,
                                              float* __restrict__ out) {
    __shared__ unsigned short As[128 * 32];
    __shared__ unsigned short Bs[128 * 32];
    const int b = blockIdx.z;
    const int o0 = blockIdx.y * 128, s0 = blockIdx.x * 128;
    const int tid = threadIdx.x;
    const int w = tid >> 6, l = tid & 63, g = l >> 4, lc = l & 15;
    const int wr = w >> 1, wc = w & 1;
    const unsigned short* ab = att + (size_t)b * 4096 * 256;

    f32x4 acc[4][4];
#pragma unroll
    for (int m = 0; m < 4; ++m)
#pragma unroll
        for (int nf = 0; nf < 4; ++nf) acc[m][nf] = (f32x4)(0.f);

    const int lrow = tid >> 1, lhalf = tid & 1;
    const int lsw0 = (lrow * 64 + lhalf * 32) ^ ((lrow & 7) << 4);
    const int lsw1 = (lrow * 64 + lhalf * 32 + 16) ^ ((lrow & 7) << 4);

    for (int kk = 0; kk < 8; ++kk) {
        const int c0 = kk * 32;
        __syncthreads();
        {
            const uint4* srcA = (const uint4*)(wpb + (size_t)(o0 + lrow) * 256 + c0 + lhalf * 16);
            uint4 a0 = srcA[0], a1 = srcA[1];
            const uint4* srcB = (const uint4*)(ab + (size_t)(s0 + lrow) * 256 + c0 + lhalf * 16);
            uint4 b0 = srcB[0], b1 = srcB[1];
            *(uint4*)((char*)As + lsw0) = a0;
            *(uint4*)((char*)As + lsw1) = a1;
            *(uint4*)((char*)Bs + lsw0) = b0;
            *(uint4*)((char*)Bs + lsw1) = b1;
        }
        __syncthreads();
        bf16x8 af[4], bfv[4];
#pragma unroll
        for (int m = 0; m < 4; ++m) {
            int row = wr * 64 + m * 16 + lc;
            af[m] = *(const bf16x8*)((char*)As + ((row * 64 + g * 16) ^ ((row & 7) << 4)));
        }
#pragma unroll
        for (int nf = 0; nf < 4; ++nf) {
            int row = wc * 64 + nf * 16 + lc;
            bfv[nf] = *(const bf16x8*)((char*)Bs + ((row * 64 + g * 16) ^ ((row & 7) << 4)));
        }
#pragma unroll
        for (int m = 0; m < 4; ++m)
#pragma unroll
            for (int nf = 0; nf < 4; ++nf)
                acc[m][nf] = __builtin_amdgcn_mfma_f32_16x16x32_bf16(af[m], bfv[nf], acc[m][nf], 0, 0, 0);
    }

#pragma unroll
    for (int m = 0; m < 4; ++m)
#pragma unroll
        for (int nf = 0; nf < 4; ++nf)
#pragma unroll
            for (int i = 0; i < 4; ++i) {
                int o = o0 + wr * 64 + m * 16 + g * 4 + i;
                int s = s0 + wc * 64 + nf * 16 + lc;
                out[((size_t)(b * 256 + o)) * 4096 + s] = acc[m][nf][i] + bp[o];
            }
}

extern "C" void kernel_launch(void* const* d_in, const int* in_sizes, int n_in,
                              void* d_out, int out_size, void* d_ws, size_t ws_size,
                              hipStream_t stream) {
    const float* x   = (const float*)d_in[0];
    const float* Wq  = (const float*)d_in[1];
    const float* bq  = (const float*)d_in[2];
    const float* Wkv = (const float*)d_in[3];
    const float* bkv = (const float*)d_in[4];
    const float* Wp  = (const float*)d_in[5];
    const float* bp  = (const float*)d_in[6];
    float* out = (float*)d_out;
    char* ws = (char*)d_ws;

    unsigned short* wb  = (unsigned short*)(ws);              // 768*256*2
    unsigned short* wpb = (unsigned short*)(ws + 393216);     // 256*256*2
    unsigned short* xT  = (unsigned short*)(ws + 524288);     // 8 MB
    unsigned short* qws = (unsigned short*)(ws + 8912896);
    unsigned short* kws = (unsigned short*)(ws + 17301504);
    unsigned short* vws = (unsigned short*)(ws + 25690112);
    unsigned short* att = (unsigned short*)(ws + 34078720);

    hipLaunchKernelGGL(k_xt, dim3(64, 4, 5), dim3(256), 0, stream, x, xT, Wq, Wkv, Wp, wb, wpb);
    hipLaunchKernelGGL(k_qkv, dim3(32, 6, 4), dim3(256), 0, stream, wb, xT, bq, bkv, qws, kws, vws);
    hipLaunchKernelGGL(k_attn, dim3(2048), dim3(128), 0, stream, qws, kws, vws, att);
    hipLaunchKernelGGL(k_proj, dim3(32, 2, 4), dim3(256), 0, stream, wpb, att, bp, out);
}

// Round 10
// 118.915 us; speedup vs baseline: 1.2934x; 1.0224x over previous
//
#include <hip/hip_runtime.h>

typedef __bf16 bf16x8 __attribute__((ext_vector_type(8)));
typedef float f32x4 __attribute__((ext_vector_type(4)));
typedef float f32x16 __attribute__((ext_vector_type(16)));

#define S_LEN 4096

__device__ __forceinline__ unsigned short f2bf(float f) {
    unsigned int u = __float_as_uint(f);
    u += 0x7fffu + ((u >> 16) & 1u);
    return (unsigned short)(u >> 16);
}

__device__ __forceinline__ unsigned int pk_bf16(float lo, float hi) {
    unsigned int r;
    asm("v_cvt_pk_bf16_f32 %0, %1, %2" : "=v"(r) : "v"(lo), "v"(hi));
    return r;
}

// ---------- x (b,c,s) f32 -> xT (b,s,c) bf16 ; z==4 slice does weight conversion ----------
__global__ __launch_bounds__(256) void k_xt(const float* __restrict__ x, unsigned short* __restrict__ xT,
                                            const float* __restrict__ Wq, const float* __restrict__ Wkv,
                                            const float* __restrict__ Wp, unsigned short* __restrict__ wb,
                                            unsigned short* __restrict__ wpb) {
    __shared__ unsigned short tile[64 * 80];
    const int tid = threadIdx.x;
    if (blockIdx.z == 4) {
        const int bi = blockIdx.x + 64 * blockIdx.y;
        for (int i = bi * 256 + tid; i < 262144; i += 65536) {
            if (i < 65536)       wb[i]           = f2bf(Wq[i]);
            else if (i < 196608) wb[i]           = f2bf(Wkv[i - 65536]);
            else                 wpb[i - 196608] = f2bf(Wp[i - 196608]);
        }
        return;
    }
    const int b = blockIdx.z, c0 = blockIdx.y * 64, s0 = blockIdx.x * 64;
#pragma unroll
    for (int ii = 0; ii < 4; ++ii) {
        int flat = ii * 256 + tid;
        int cr = flat >> 4, s4 = flat & 15;
        const float4 v = *(const float4*)(x + ((size_t)(b * 256 + c0 + cr)) * S_LEN + s0 + s4 * 4);
        tile[(s4 * 4 + 0) * 80 + cr] = f2bf(v.x);
        tile[(s4 * 4 + 1) * 80 + cr] = f2bf(v.y);
        tile[(s4 * 4 + 2) * 80 + cr] = f2bf(v.z);
        tile[(s4 * 4 + 3) * 80 + cr] = f2bf(v.w);
    }
    __syncthreads();
#pragma unroll
    for (int ii = 0; ii < 2; ++ii) {
        int flat = ii * 256 + tid;
        int sr = flat >> 3, ch = flat & 7;
        uint4 u = *(const uint4*)&tile[sr * 80 + ch * 8];
        *(uint4*)(xT + ((size_t)(b * 4096 + s0 + sr)) * 256 + c0 + ch * 8) = u;
    }
}

// ---------- QKV GEMM -> q (pre-scaled) / k [b][h][s][32], v [b][h][32][s] ----------
__global__ __launch_bounds__(256) void k_qkv(const unsigned short* __restrict__ wb,
                                             const unsigned short* __restrict__ xT,
                                             const float* __restrict__ bq,
                                             const float* __restrict__ bkv,
                                             unsigned short* __restrict__ qws,
                                             unsigned short* __restrict__ kws,
                                             unsigned short* __restrict__ vws) {
    __shared__ unsigned short As[128 * 32];
    __shared__ unsigned short Bs[128 * 32];
    const int b = blockIdx.z;
    const int o0 = blockIdx.y * 128, s0 = blockIdx.x * 128;
    const int tid = threadIdx.x;
    const int w = tid >> 6, l = tid & 63, g = l >> 4, lc = l & 15;
    const int wr = w >> 1, wc = w & 1;
    const unsigned short* xb = xT + (size_t)b * 4096 * 256;
    const float SM_C = 0.25505654458f;  // log2(e)/sqrt(32) folded into q

    f32x4 acc[4][4];
#pragma unroll
    for (int m = 0; m < 4; ++m)
#pragma unroll
        for (int nf = 0; nf < 4; ++nf) acc[m][nf] = (f32x4)(0.f);

    const int lrow = tid >> 1, lhalf = tid & 1;
    const int lsw0 = (lrow * 64 + lhalf * 32) ^ ((lrow & 7) << 4);
    const int lsw1 = (lrow * 64 + lhalf * 32 + 16) ^ ((lrow & 7) << 4);

    for (int kk = 0; kk < 8; ++kk) {
        const int c0 = kk * 32;
        __syncthreads();
        {
            const uint4* srcA = (const uint4*)(wb + (size_t)(o0 + lrow) * 256 + c0 + lhalf * 16);
            uint4 a0 = srcA[0], a1 = srcA[1];
            const uint4* srcB = (const uint4*)(xb + (size_t)(s0 + lrow) * 256 + c0 + lhalf * 16);
            uint4 b0 = srcB[0], b1 = srcB[1];
            *(uint4*)((char*)As + lsw0) = a0;
            *(uint4*)((char*)As + lsw1) = a1;
            *(uint4*)((char*)Bs + lsw0) = b0;
            *(uint4*)((char*)Bs + lsw1) = b1;
        }
        __syncthreads();
        bf16x8 af[4], bfv[4];
#pragma unroll
        for (int m = 0; m < 4; ++m) {
            int row = wr * 64 + m * 16 + lc;
            af[m] = *(const bf16x8*)((char*)As + ((row * 64 + g * 16) ^ ((row & 7) << 4)));
        }
#pragma unroll
        for (int nf = 0; nf < 4; ++nf) {
            int row = wc * 64 + nf * 16 + lc;
            bfv[nf] = *(const bf16x8*)((char*)Bs + ((row * 64 + g * 16) ^ ((row & 7) << 4)));
        }
#pragma unroll
        for (int m = 0; m < 4; ++m)
#pragma unroll
            for (int nf = 0; nf < 4; ++nf)
                acc[m][nf] = __builtin_amdgcn_mfma_f32_16x16x32_bf16(af[m], bfv[nf], acc[m][nf], 0, 0, 0);
    }

#pragma unroll
    for (int m = 0; m < 4; ++m)
#pragma unroll
        for (int nf = 0; nf < 4; ++nf)
#pragma unroll
            for (int i = 0; i < 4; ++i) {
                int o = o0 + wr * 64 + m * 16 + g * 4 + i;
                int s = s0 + wc * 64 + nf * 16 + lc;
                if (o < 256) {
                    int h = o >> 5, d = o & 31;
                    qws[(((size_t)(b * 8 + h)) * 4096 + s) * 32 + d] = f2bf((acc[m][nf][i] + bq[o]) * SM_C);
                } else if (o < 512) {
                    int oo = o - 256, h = oo >> 5, d = oo & 31;
                    kws[(((size_t)(b * 8 + h)) * 4096 + s) * 32 + d] = f2bf(acc[m][nf][i] + bkv[o - 256]);
                } else {
                    int oo = o - 512, h = oo >> 5, d = oo & 31;
                    vws[(((size_t)(b * 8 + h)) * 32 + d) * 4096 + s] = f2bf(acc[m][nf][i] + bkv[o - 256]);
                }
            }
}

// ---------- causal flash attention: 128-q block (4 waves), K direct from global (R8-proven),
// ---------- V LDS-dbuf (R8-proven layout), 128-key rounds, balanced mt schedule ----------
#define VC_STRIDE 544
#define BUF_STRIDE 8704   // 16 * 544

__device__ __forceinline__ void attn_sub(const unsigned short* __restrict__ kw_bh, int key0,
                                         const char* __restrict__ vbuf, int c,
                                         bf16x8 qf0, bf16x8 qf1, const f32x16& zf, bf16x8 ones,
                                         int lane31, int hh, bool domask,
                                         f32x16& o, f32x16& sums) {
    const unsigned short* kp = kw_bh + (size_t)(key0 + lane31) * 32 + hh * 8;
    bf16x8 kf0 = *(const bf16x8*)(kp);
    bf16x8 kf1 = *(const bf16x8*)(kp + 16);
    bf16x8 vf0 = *(const bf16x8*)(vbuf + (c * 4 + hh) * VC_STRIDE + lane31 * 16);
    bf16x8 vf1 = *(const bf16x8*)(vbuf + (c * 4 + 2 + hh) * VC_STRIDE + lane31 * 16);

    f32x16 s = __builtin_amdgcn_mfma_f32_32x32x16_bf16(kf0, qf0, zf, 0, 0, 0);
    s = __builtin_amdgcn_mfma_f32_32x32x16_bf16(kf1, qf1, s, 0, 0, 0);

    if (domask) {
#pragma unroll
        for (int r = 0; r < 16; ++r) {
            int krel = (r & 3) + 8 * (r >> 2) + 4 * hh;
            if (krel > lane31) s[r] = -1e30f;
        }
    }

    float p[16];
#pragma unroll
    for (int r = 0; r < 16; ++r) p[r] = __builtin_amdgcn_exp2f(s[r]);

    unsigned int c00 = pk_bf16(p[0], p[1]),   c01 = pk_bf16(p[2], p[3]);
    unsigned int c10 = pk_bf16(p[4], p[5]),   c11 = pk_bf16(p[6], p[7]);
    unsigned int c20 = pk_bf16(p[8], p[9]),   c21 = pk_bf16(p[10], p[11]);
    unsigned int c30 = pk_bf16(p[12], p[13]), c31 = pk_bf16(p[14], p[15]);
    asm("v_permlane32_swap_b32 %0, %1" : "+v"(c00), "+v"(c10));
    asm("v_permlane32_swap_b32 %0, %1" : "+v"(c01), "+v"(c11));
    asm("v_permlane32_swap_b32 %0, %1" : "+v"(c20), "+v"(c30));
    asm("v_permlane32_swap_b32 %0, %1" : "+v"(c21), "+v"(c31));
    union U { uint4 u; bf16x8 v; };
    U pa0, pa1;
    pa0.u = make_uint4(c00, c01, c10, c11);
    pa1.u = make_uint4(c20, c21, c30, c31);

    sums = __builtin_amdgcn_mfma_f32_32x32x16_bf16(ones, pa0.v, sums, 0, 0, 0);
    sums = __builtin_amdgcn_mfma_f32_32x32x16_bf16(ones, pa1.v, sums, 0, 0, 0);
    o = __builtin_amdgcn_mfma_f32_32x32x16_bf16(vf0, pa0.v, o, 0, 0, 0);
    o = __builtin_amdgcn_mfma_f32_32x32x16_bf16(vf1, pa1.v, o, 0, 0, 0);
}

__global__ __launch_bounds__(256, 4) void k_attn(const unsigned short* __restrict__ qw,
                                                 const unsigned short* __restrict__ kw,
                                                 const unsigned short* __restrict__ vw,
                                                 unsigned short* __restrict__ att) {
    __shared__ __align__(16) char smem[2 * BUF_STRIDE];

    const int tid = threadIdx.x;
    const int w = tid >> 6, l = tid & 63;
    const int lane31 = l & 31, hh = l >> 5;

    // XCD pinning (validated R4). Balanced per-CU mt sets {e, 31-e, 8+e, 23-e} (sum 62).
    const int B = blockIdx.x;
    const int xcd = B & 7, idx = B >> 3;       // idx in [0,128)
    const int bh = xcd * 4 + (idx & 3);
    const int v4 = idx >> 2;                   // [0,32)
    const int j4 = v4 >> 3, d4 = v4 & 7;
    const int mt = (j4 & 1) ? (31 - 8 * (j4 >> 1) - d4) : (8 * (j4 >> 1) + d4);

    const int q = mt * 128 + w * 32 + lane31;

    const unsigned short* qw_bh = qw + (size_t)bh * 4096 * 32;
    const unsigned short* kw_bh = kw + (size_t)bh * 4096 * 32;
    const unsigned short* vw_bh = vw + (size_t)bh * 32 * 4096;

    const bf16x8 qf0 = *(const bf16x8*)(qw_bh + (size_t)q * 32 + hh * 8);
    const bf16x8 qf1 = *(const bf16x8*)(qw_bh + (size_t)q * 32 + hh * 8 + 16);

    // V staging: 256 threads x 2 x 16B per 128-key round (R8 layout, 256-thread split)
    const unsigned short* vsrc = vw_bh + (size_t)(tid >> 4) * 4096 + (tid & 15) * 8;
    const int vd0 = (tid & 15) * VC_STRIDE + (tid >> 4) * 16;

    f32x16 o, sums, zf;
#pragma unroll
    for (int r = 0; r < 16; ++r) { o[r] = 0.f; sums[r] = 0.f; zf[r] = 0.f; }

    union OU { unsigned int u[4]; bf16x8 v; };
    OU onesU;
#pragma unroll
    for (int jj = 0; jj < 4; ++jj) onesU.u[jj] = 0x3F803F80u;  // bf16 1.0 x2
    const bf16x8 ones = onesU.v;

    // prologue: stage round 0 into buf0
    {
        uint4 va = *(const uint4*)(vsrc);
        uint4 vbb = *(const uint4*)(vsrc + 65536);   // d + 16
        *(uint4*)(smem + vd0)       = va;
        *(uint4*)(smem + vd0 + 256) = vbb;
    }

    int cur = 0;
    // main rounds: all 4 subs causally full for all 4 waves
    for (int r = 0; r < mt; ++r) {
        const unsigned short* vp = vsrc + (size_t)(r + 1) * 128;
        uint4 va = *(const uint4*)(vp);
        uint4 vbb = *(const uint4*)(vp + 65536);

        __syncthreads();
        const char* vbuf = smem + cur * BUF_STRIDE;
        const int k0 = r * 128;
        attn_sub(kw_bh, k0,      vbuf, 0, qf0, qf1, zf, ones, lane31, hh, false, o, sums);
        attn_sub(kw_bh, k0 + 32, vbuf, 1, qf0, qf1, zf, ones, lane31, hh, false, o, sums);
        attn_sub(kw_bh, k0 + 64, vbuf, 2, qf0, qf1, zf, ones, lane31, hh, false, o, sums);
        attn_sub(kw_bh, k0 + 96, vbuf, 3, qf0, qf1, zf, ones, lane31, hh, false, o, sums);

        char* nb = smem + (cur ^ 1) * BUF_STRIDE;
        *(uint4*)(nb + vd0)       = va;
        *(uint4*)(nb + vd0 + 256) = vbb;
        cur ^= 1;
    }

    __syncthreads();
    // last round (keys 128mt..128mt+127): wave w runs subs 0..w, diagonal mask at c==w
    {
        const char* vbuf = smem + cur * BUF_STRIDE;
        const int k0 = mt * 128;
#pragma unroll
        for (int c = 0; c < 4; ++c)
            if (c <= w)
                attn_sub(kw_bh, k0 + 32 * c, vbuf, c, qf0, qf1, zf, ones, lane31, hh, c == w, o, sums);
    }

    const float inv = 1.0f / sums[0];
    unsigned int* dst = (unsigned int*)(att + (((size_t)(bh >> 3)) * 4096 + q) * 256 + (bh & 7) * 32);
#pragma unroll
    for (int jj = 0; jj < 8; ++jj) {
        unsigned int v = pk_bf16(o[2 * jj] * inv, o[2 * jj + 1] * inv);
        dst[(jj & 1) + 4 * (jj >> 1) + 2 * hh] = v;
    }
}

// ---------- output projection ----------
__global__ __launch_bounds__(256) void k_proj(const unsigned short* __restrict__ wpb,
                                              const unsigned short* __restrict__ att,
                                              const float* __restrict__ bp,
                                              float* __restrict__ out) {
    __shared__ unsigned short As[128 * 32];
    __shared__ unsigned short Bs[128 * 32];
    const int b = blockIdx.z;
    const int o0 = blockIdx.y * 128, s0 = blockIdx.x * 128;
    const int tid = threadIdx.x;
    const int w = tid >> 6, l = tid & 63, g = l >> 4, lc = l & 15;
    const int wr = w >> 1, wc = w & 1;
    const unsigned short* ab = att + (size_t)b * 4096 * 256;

    f32x4 acc[4][4];
#pragma unroll
    for (int m = 0; m < 4; ++m)
#pragma unroll
        for (int nf = 0; nf < 4; ++nf) acc[m][nf] = (f32x4)(0.f);

    const int lrow = tid >> 1, lhalf = tid & 1;
    const int lsw0 = (lrow * 64 + lhalf * 32) ^ ((lrow & 7) << 4);
    const int lsw1 = (lrow * 64 + lhalf * 32 + 16) ^ ((lrow & 7) << 4);

    for (int kk = 0; kk < 8; ++kk) {
        const int c0 = kk * 32;
        __syncthreads();
        {
            const uint4* srcA = (const uint4*)(wpb + (size_t)(o0 + lrow) * 256 + c0 + lhalf * 16);
            uint4 a0 = srcA[0], a1 = srcA[1];
            const uint4* srcB = (const uint4*)(ab + (size_t)(s0 + lrow) * 256 + c0 + lhalf * 16);
            uint4 b0 = srcB[0], b1 = srcB[1];
            *(uint4*)((char*)As + lsw0) = a0;
            *(uint4*)((char*)As + lsw1) = a1;
            *(uint4*)((char*)Bs + lsw0) = b0;
            *(uint4*)((char*)Bs + lsw1) = b1;
        }
        __syncthreads();
        bf16x8 af[4], bfv[4];
#pragma unroll
        for (int m = 0; m < 4; ++m) {
            int row = wr * 64 + m * 16 + lc;
            af[m] = *(const bf16x8*)((char*)As + ((row * 64 + g * 16) ^ ((row & 7) << 4)));
        }
#pragma unroll
        for (int nf = 0; nf < 4; ++nf) {
            int row = wc * 64 + nf * 16 + lc;
            bfv[nf] = *(const bf16x8*)((char*)Bs + ((row * 64 + g * 16) ^ ((row & 7) << 4)));
        }
#pragma unroll
        for (int m = 0; m < 4; ++m)
#pragma unroll
            for (int nf = 0; nf < 4; ++nf)
                acc[m][nf] = __builtin_amdgcn_mfma_f32_16x16x32_bf16(af[m], bfv[nf], acc[m][nf], 0, 0, 0);
    }

#pragma unroll
    for (int m = 0; m < 4; ++m)
#pragma unroll
        for (int nf = 0; nf < 4; ++nf)
#pragma unroll
            for (int i = 0; i < 4; ++i) {
                int o = o0 + wr * 64 + m * 16 + g * 4 + i;
                int s = s0 + wc * 64 + nf * 16 + lc;
                out[((size_t)(b * 256 + o)) * 4096 + s] = acc[m][nf][i] + bp[o];
            }
}

extern "C" void kernel_launch(void* const* d_in, const int* in_sizes, int n_in,
                              void* d_out, int out_size, void* d_ws, size_t ws_size,
                              hipStream_t stream) {
    const float* x   = (const float*)d_in[0];
    const float* Wq  = (const float*)d_in[1];
    const float* bq  = (const float*)d_in[2];
    const float* Wkv = (const float*)d_in[3];
    const float* bkv = (const float*)d_in[4];
    const float* Wp  = (const float*)d_in[5];
    const float* bp  = (const float*)d_in[6];
    float* out = (float*)d_out;
    char* ws = (char*)d_ws;

    unsigned short* wb  = (unsigned short*)(ws);              // 768*256*2
    unsigned short* wpb = (unsigned short*)(ws + 393216);     // 256*256*2
    unsigned short* xT  = (unsigned short*)(ws + 524288);     // 8 MB
    unsigned short* qws = (unsigned short*)(ws + 8912896);
    unsigned short* kws = (unsigned short*)(ws + 17301504);
    unsigned short* vws = (unsigned short*)(ws + 25690112);
    unsigned short* att = (unsigned short*)(ws + 34078720);

    hipLaunchKernelGGL(k_xt, dim3(64, 4, 5), dim3(256), 0, stream, x, xT, Wq, Wkv, Wp, wb, wpb);
    hipLaunchKernelGGL(k_qkv, dim3(32, 6, 4), dim3(256), 0, stream, wb, xT, bq, bkv, qws, kws, vws);
    hipLaunchKernelGGL(k_attn, dim3(1024), dim3(256), 0, stream, qws, kws, vws, att);
    hipLaunchKernelGGL(k_proj, dim3(32, 2, 4), dim3(256), 0, stream, wpb, att, bp, out);
}